// Round 7
// baseline (315.964 us; speedup 1.0000x reference)
//
#include <hip/hip_runtime.h>
#include <math.h>

#define NFFT 512
#define HOP 128
#define NBINS 257
#define ROW 1028          // 4*257
#define CHUNK 128
#define LAM128 0.0391373f // 0.975^128 (exact cross-chunk decay)
// LDS swizzle for FFT buffers: bijective, applied to EVERY access.
// Reads (consecutive k across lanes) stay conflict-free; stride-4 butterfly
// writes (ds=0,1) drop from 16-way to ~2-way.
#define SWZ(a) ((a) ^ (((a) >> 4) & 15))

__device__ __forceinline__ float2 cmul(float2 a, float2 b) {
  return make_float2(a.x * b.x - a.y * b.y, a.x * b.y + a.y * b.x);
}

// ---------- prep: twiddle table (once) + sparse filterbank spans ----------
__global__ void k_prep(const float* __restrict__ fb, int* __restrict__ lohi,
                       float2* __restrict__ twg) {
  int t = threadIdx.x;
  for (int i = t; i < NFFT; i += 256) {
    double ang = -6.283185307179586476925286766559 * (double)i / (double)NFFT;
    twg[i] = make_float2((float)cos(ang), (float)sin(ang));
  }
  for (int m = t; m < NBINS; m += 256) {
    int lo = 0, hi = -1;
    for (int f = 0; f < NBINS; ++f) {
      if (fb[f * NBINS + m] != 0.0f) { if (hi < 0) lo = f; hi = f; }
    }
    lohi[m] = lo;
    lohi[NBINS + m] = hi;
  }
}

// ---------- per-bin epilogue (S = swizzled LDS array, off = subarray base) ----------
__device__ __forceinline__ void epilogue_bin(const float2* __restrict__ S, int off,
                                             float* __restrict__ mspec,
                                             float* __restrict__ out, unsigned ob,
                                             int k, bool store) {
  float2 z = S[SWZ(off + k)];
  float mag, sv, cv;
  if (k == 0 || k == 256) {
    // z.y is EXACTLY 0 here (unpack cancels identically at k==m). The f32
    // reference computes sin(atan2(+0, re)) = sin(pi_f32) = -8.742278e-8 when
    // re<0 — NOT 0. F.normalize scales that column to -1/sqrt(N_neg), so we
    // must emit the same tiny values for the norm to match.
    mag = fabsf(z.x);
    sv = sinf(atan2f(0.0f, z.x));
    cv = copysignf(1.0f, z.x);
  } else {
    mag = sqrtf(z.x * z.x + z.y * z.y);
    float inv = (mag > 0.0f) ? 1.0f / mag : 0.0f;
    sv = (mag > 0.0f) ? z.y * inv : 0.0f;   // sin(angle) = im/|z|
    cv = (mag > 0.0f) ? z.x * inv : 1.0f;   // cos(angle) = re/|z|
  }
  if (store) {
    out[ob + k] = logf(mag + 1e-9f);
    out[ob + 2 * NBINS + k] = sv;
    out[ob + 3 * NBINS + k] = cv;
  }
  // hann spectrum via 3-tap stencil; X[-1] = conj(X[1])
  float2 zm, zp;
  if (k == 0) { float2 s1 = S[SWZ(off + 1)]; zm = make_float2(s1.x, -s1.y); }
  else zm = S[SWZ(off + k - 1)];
  zp = S[SWZ(off + k + 1)];
  float hr = 0.5f * z.x - 0.25f * (zm.x + zp.x);
  float hi = 0.5f * z.y - 0.25f * (zm.y + zp.y);
  mspec[k] = hr * hr + hi * hi;
}

// ---------- 4 frames per block: 2 complex FFTs, radix-4 (fused 2x radix-2) ----------
// Fused double-stage derivation (verified at N=8 incl. the -i path):
//   thread v=qm+r: E0=s02+s13 -> z[4qm+r]; E1=W^qm(d02-i*d13) -> +m;
//   E2=W^2qm(s02-s13) -> +2m;  E3=W^3qm(d02+i*d13) -> +3m.
__global__ __launch_bounds__(256) void k_fft(
    const float* __restrict__ audio, const float* __restrict__ fb,
    const int* __restrict__ lohi, const float2* __restrict__ twg,
    float* __restrict__ out, int T, int nframes) {
  __shared__ float2 bufA[2][520];
  __shared__ float2 bufB[2][520];
  __shared__ float2 twL[NFFT];
  __shared__ float mspec[4][NBINS];

  const int t = threadIdx.x;
  const int ff = t >> 7;       // which FFT (0/1)
  const int v = t & 127;       // butterfly index within FFT
  const int frb = blockIdx.x * 4;
  const int fr0 = frb + 2 * ff;
  const int fr1 = fr0 + 1;
  const bool h0 = fr0 < nframes;
  const bool h1 = fr1 < nframes;

  for (int i = t; i < NFFT; i += 256) twL[i] = twg[i];

  float2* __restrict__ xa = bufA[ff];
  float2* __restrict__ xb = bufB[ff];

  // load packed frame pair with reflect padding: z = frame0 + i*frame1
  int s0 = fr0 * HOP - NFFT / 2;
  for (int i = v; i < NFFT; i += 128) {
    int q0 = s0 + i;
    if (q0 < 0) q0 = -q0;
    if (q0 >= T) q0 = 2 * T - 2 - q0;
    int q1 = s0 + HOP + i;
    if (q1 < 0) q1 = -q1;
    if (q1 >= T) q1 = 2 * T - 2 - q1;
    xa[SWZ(i)] = make_float2(audio[q0], h1 ? audio[q1] : 0.0f);
  }
  __syncthreads();

  float2 *x = xa, *y = xb;
#pragma unroll
  for (int ds = 0; ds < 4; ++ds) {
    const int m = 1 << (2 * ds);
    int qm = v & ~(m - 1);
    int r = v - qm;
    int o = 4 * qm + r;
    float2 x0 = x[SWZ(v)], x1 = x[SWZ(v + 128)], x2 = x[SWZ(v + 256)], x3 = x[SWZ(v + 384)];
    float2 s02 = make_float2(x0.x + x2.x, x0.y + x2.y);
    float2 d02 = make_float2(x0.x - x2.x, x0.y - x2.y);
    float2 s13 = make_float2(x1.x + x3.x, x1.y + x3.y);
    float2 d13 = make_float2(x1.x - x3.x, x1.y - x3.y);
    float2 E0 = make_float2(s02.x + s13.x, s02.y + s13.y);
    float2 u1 = make_float2(d02.x + d13.y, d02.y - d13.x);  // d02 - i*d13
    float2 u2 = make_float2(s02.x - s13.x, s02.y - s13.y);
    float2 u3 = make_float2(d02.x - d13.y, d02.y + d13.x);  // d02 + i*d13
    float2 E1 = cmul(twL[qm], u1);
    float2 E2 = cmul(twL[2 * qm], u2);
    float2 E3 = cmul(twL[3 * qm], u3);
    y[SWZ(o)] = E0;
    y[SWZ(o + m)] = E1;
    y[SWZ(o + 2 * m)] = E2;
    y[SWZ(o + 3 * m)] = E3;
    __syncthreads();
    float2* tmp = x; x = y; y = tmp;
  }
  // final radix-2 stage (m=256, twiddle=1): two butterflies per thread
#pragma unroll
  for (int j = 0; j < 2; ++j) {
    int b = v + 128 * j;
    float2 c0 = x[SWZ(b)], c1 = x[SWZ(b + 256)];
    y[SWZ(b)] = make_float2(c0.x + c1.x, c0.y + c1.y);
    y[SWZ(b + 256)] = make_float2(c0.x - c1.x, c0.y - c1.y);
  }
  __syncthreads();

  // unpack into x (free buffer): X1 (frame fr0) at [0..257], X2 (fr1) at [258..515]
  for (int k = v; k < 258; k += 128) {
    int m2 = (NFFT - k) & (NFFT - 1);
    float2 Zk = y[SWZ(k)], Zm = y[SWZ(m2)];
    x[SWZ(k)] = make_float2(0.5f * (Zk.x + Zm.x), 0.5f * (Zk.y - Zm.y));
    x[SWZ(258 + k)] = make_float2(0.5f * (Zk.y + Zm.y), 0.5f * (Zm.x - Zk.x));
  }
  __syncthreads();

  unsigned ob0 = (unsigned)fr0 * ROW;
  unsigned ob1 = (unsigned)fr1 * ROW;
  for (int k = v; k < NBINS; k += 128) {
    epilogue_bin(x, 0, mspec[2 * ff], out, ob0, k, h0);
    epilogue_bin(x, 258, mspec[2 * ff + 1], out, ob1, k, h1);
  }
  __syncthreads();

  // sparse mel for both frames of this FFT
  for (int m = v; m < NBINS; m += 128) {
    int lo = lohi[m], hi = lohi[NBINS + m];
    float a0 = 0.0f, a1 = 0.0f;
    for (int f = lo; f <= hi; ++f) {
      float w = fb[f * NBINS + m];
      a0 = fmaf(mspec[2 * ff][f], w, a0);
      a1 = fmaf(mspec[2 * ff + 1][f], w, a1);
    }
    if (h0) out[ob0 + NBINS + m] = a0;
    if (h1) out[ob1 + NBINS + m] = a1;
  }
}

// ---------- pcen phase A: local chunk scan from zero -> mend ----------
__global__ __launch_bounds__(320) void k_pcen_a(const float* __restrict__ out,
                                                float* __restrict__ mend, int nframes) {
  int m = threadIdx.x;
  if (m >= NBINS) return;
  int c = blockIdx.x;
  int F0 = c * CHUNK;
  int end = min(F0 + CHUNK, nframes);
  const float SS = 0.025f, OMS = 1.0f - SS;
  float mm = 0.0f;
  int tf = F0;
  for (; tf + 16 <= end; tf += 16) {
    float xs[16];
#pragma unroll
    for (int j = 0; j < 16; ++j) xs[j] = out[(unsigned)(tf + j) * ROW + NBINS + m];
#pragma unroll
    for (int j = 0; j < 16; ++j) mm = OMS * mm + SS * xs[j];
  }
  for (; tf < end; ++tf) mm = OMS * mm + SS * out[(unsigned)tf * ROW + NBINS + m];
  mend[c * NBINS + m] = mm;
}

// ---------- pcen phase B: exact cross-chunk scan (tiny) ----------
__global__ void k_pcen_b(const float* __restrict__ mend, float* __restrict__ vinit,
                         int chunks) {
  int m = threadIdx.x;
  if (m >= NBINS) return;
  float v = 0.0f;
  vinit[m] = 0.0f;
  for (int c = 1; c < chunks; ++c) {
    v = mend[(c - 1) * NBINS + m] + LAM128 * v;  // m_end(c-1) exact composition
    vinit[c * NBINS + m] = v;
  }
}

// ---------- pcen phase C: apply with exact init ----------
__global__ __launch_bounds__(320) void k_pcen_c(float* __restrict__ out,
                                                const float* __restrict__ vinit,
                                                int nframes) {
  int m = threadIdx.x;
  if (m >= NBINS) return;
  int c = blockIdx.x;
  int F0 = c * CHUNK;
  int end = min(F0 + CHUNK, nframes);
  const float SS = 0.025f, OMS = 1.0f - SS;
  const float SQ2 = sqrtf(2.0f);
  float mm = vinit[c * NBINS + m];
  int tf = F0;
  for (; tf + 16 <= end; tf += 16) {
    float xs[16], ys[16];
#pragma unroll
    for (int j = 0; j < 16; ++j) xs[j] = out[(unsigned)(tf + j) * ROW + NBINS + m];
#pragma unroll
    for (int j = 0; j < 16; ++j) {
      mm = OMS * mm + SS * xs[j];
      float den = expf(0.98f * logf(mm + 1e-6f));
      ys[j] = sqrtf(xs[j] / den + 2.0f) - SQ2;
    }
#pragma unroll
    for (int j = 0; j < 16; ++j) out[(unsigned)(tf + j) * ROW + NBINS + m] = ys[j];
  }
  for (; tf < end; ++tf) {
    unsigned idx = (unsigned)tf * ROW + NBINS + m;
    float xv = out[idx];
    mm = OMS * mm + SS * xv;
    float den = expf(0.98f * logf(mm + 1e-6f));
    out[idx] = sqrtf(xv / den + 2.0f) - SQ2;
  }
}

// ---------- column sum-of-squares partials (deterministic, no atomics) ----------
__global__ __launch_bounds__(256) void k_sumsq(const float* __restrict__ out,
                                               float* __restrict__ part,
                                               int nframes, int nblk) {
  int b = blockIdx.x, t = threadIdx.x;
  int per = (nframes + nblk - 1) / nblk;
  int f0 = b * per;
  int f1 = min(f0 + per, nframes);
  float acc[5] = {0.f, 0.f, 0.f, 0.f, 0.f};
  int f = f0;
  for (; f + 2 <= f1; f += 2) {
    unsigned ba = (unsigned)f * ROW, bb = ba + ROW;
    float va[4], vb[4];
#pragma unroll
    for (int j = 0; j < 4; ++j) va[j] = out[ba + t + 256 * j];
#pragma unroll
    for (int j = 0; j < 4; ++j) vb[j] = out[bb + t + 256 * j];
    float wa = 0.f, wb = 0.f;
    if (t < ROW - 1024) { wa = out[ba + 1024 + t]; wb = out[bb + 1024 + t]; }
#pragma unroll
    for (int j = 0; j < 4; ++j) {
      acc[j] = fmaf(va[j], va[j], acc[j]);
      acc[j] = fmaf(vb[j], vb[j], acc[j]);
    }
    acc[4] = fmaf(wa, wa, acc[4]);
    acc[4] = fmaf(wb, wb, acc[4]);
  }
  for (; f < f1; ++f) {
    unsigned ba = (unsigned)f * ROW;
#pragma unroll
    for (int j = 0; j < 4; ++j) {
      float vv = out[ba + t + 256 * j];
      acc[j] = fmaf(vv, vv, acc[j]);
    }
    if (t < ROW - 1024) {
      float vv = out[ba + 1024 + t];
      acc[4] = fmaf(vv, vv, acc[4]);
    }
  }
#pragma unroll
  for (int j = 0; j < 4; ++j) part[(unsigned)b * ROW + t + 256 * j] = acc[j];
  if (t < ROW - 1024) part[(unsigned)b * ROW + 1024 + t] = acc[4];
}

// ---------- finalize norms: one block per column, LDS tree (deterministic) ----------
__global__ __launch_bounds__(256) void k_norm(const float* __restrict__ part,
                                              float* __restrict__ invn, int nblk) {
  __shared__ float red[256];
  int c = blockIdx.x, t = threadIdx.x;
  float s = 0.0f;
  for (int b = t; b < nblk; b += 256) s += part[(unsigned)b * ROW + c];
  red[t] = s;
  __syncthreads();
  for (int o = 128; o > 0; o >>= 1) {
    if (t < o) red[t] += red[t + o];
    __syncthreads();
  }
  if (t == 0) invn[c] = 1.0f / fmaxf(sqrtf(red[0]), 1e-12f);
}

// ---------- scale pass ----------
__global__ __launch_bounds__(256) void k_scale(float4* __restrict__ out4,
                                               const float* __restrict__ invn,
                                               long n4) {
  __shared__ float inv[ROW];
  for (int i = threadIdx.x; i < ROW; i += 256) inv[i] = invn[i];
  __syncthreads();
  long stride = (long)gridDim.x * 256;
  for (long i = (long)blockIdx.x * 256 + threadIdx.x; i < n4; i += stride) {
    float4 v = out4[i];
    int col = (int)((i * 4) % ROW);
    v.x *= inv[col];
    v.y *= inv[col + 1];
    v.z *= inv[col + 2];
    v.w *= inv[col + 3];
    out4[i] = v;
  }
}

extern "C" void kernel_launch(void* const* d_in, const int* in_sizes, int n_in,
                              void* d_out, int out_size, void* d_ws, size_t ws_size,
                              hipStream_t stream) {
  const float* audio = (const float*)d_in[0];
  const float* fb = (const float*)d_in[1];
  int T = in_sizes[0];
  int nframes = 1 + T / HOP;  // center=True, pad = NFFT/2 both sides
  float* out = (float*)d_out;
  int chunks = (nframes + CHUNK - 1) / CHUNK;

  // ws layout (floats): twg[1024] | mend[chunks*257] | vinit[chunks*257] |
  //                     invn[1028] | lohi[514](int) | part[nblk*1028]
  float* wsf = (float*)d_ws;
  float2* twg = (float2*)wsf;
  float* mend = wsf + 1024;
  float* vinit = mend + (long)chunks * NBINS;
  float* invn = vinit + (long)chunks * NBINS;
  int* lohi = (int*)(invn + ROW);
  float* part = (float*)(lohi + 2 * NBINS);
  long base = 1024 + 2L * chunks * NBINS + ROW + 2 * NBINS;
  long avail = (long)(ws_size / 4) - base - 64;
  int nblk = 1024;
  while (nblk > 64 && (long)nblk * ROW > avail) nblk >>= 1;

  k_prep<<<1, 256, 0, stream>>>(fb, lohi, twg);
  k_fft<<<(nframes + 3) / 4, 256, 0, stream>>>(audio, fb, lohi, twg, out, T, nframes);
  k_pcen_a<<<chunks, 320, 0, stream>>>(out, mend, nframes);
  k_pcen_b<<<1, 320, 0, stream>>>(mend, vinit, chunks);
  k_pcen_c<<<chunks, 320, 0, stream>>>(out, vinit, nframes);
  k_sumsq<<<nblk, 256, 0, stream>>>(out, part, nframes, nblk);
  k_norm<<<ROW, 256, 0, stream>>>(part, invn, nblk);
  long n4 = (long)nframes * ROW / 4;
  k_scale<<<2048, 256, 0, stream>>>((float4*)out, invn, n4);
}

// Round 8
// 252.821 us; speedup vs baseline: 1.2498x; 1.2498x over previous
//
#include <hip/hip_runtime.h>
#include <math.h>

#define NFFT 512
#define HOP 128
#define NBINS 257
#define ROW 1028          // 4*257
#define CHUNK 128
#define LAM128 0.0391373f // 0.975^128 (exact cross-chunk decay)
// LDS swizzle for FFT buffers: bijective, applied to EVERY access.
#define SWZ(a) ((a) ^ (((a) >> 4) & 15))

__device__ __forceinline__ float2 cmul(float2 a, float2 b) {
  return make_float2(a.x * b.x - a.y * b.y, a.x * b.y + a.y * b.x);
}

// ---------- prep: twiddle table (once) + sparse filterbank spans ----------
__global__ void k_prep(const float* __restrict__ fb, int* __restrict__ lohi,
                       float2* __restrict__ twg) {
  int t = threadIdx.x;
  for (int i = t; i < NFFT; i += 256) {
    double ang = -6.283185307179586476925286766559 * (double)i / (double)NFFT;
    twg[i] = make_float2((float)cos(ang), (float)sin(ang));
  }
  for (int m = t; m < NBINS; m += 256) {
    int lo = 0, hi = -1;
    for (int f = 0; f < NBINS; ++f) {
      if (fb[f * NBINS + m] != 0.0f) { if (hi < 0) lo = f; hi = f; }
    }
    lohi[m] = lo;
    lohi[NBINS + m] = hi;
  }
}

// ---------- per-bin epilogue (S = swizzled LDS array, off = subarray base) ----------
__device__ __forceinline__ void epilogue_bin(const float2* __restrict__ S, int off,
                                             float* __restrict__ mspec,
                                             float* __restrict__ out, unsigned ob,
                                             int k, bool store) {
  float2 z = S[SWZ(off + k)];
  float mag, sv, cv;
  if (k == 0 || k == 256) {
    // z.y is EXACTLY 0 here (unpack cancels identically at k==m). The f32
    // reference computes sin(atan2(+0, re)) = sin(pi_f32) = -8.742278e-8 when
    // re<0 — NOT 0. F.normalize scales that column to -1/sqrt(N_neg), so we
    // must emit the same tiny values for the norm to match.
    mag = fabsf(z.x);
    sv = sinf(atan2f(0.0f, z.x));
    cv = copysignf(1.0f, z.x);
  } else {
    mag = sqrtf(z.x * z.x + z.y * z.y);
    float inv = (mag > 0.0f) ? 1.0f / mag : 0.0f;
    sv = (mag > 0.0f) ? z.y * inv : 0.0f;   // sin(angle) = im/|z|
    cv = (mag > 0.0f) ? z.x * inv : 1.0f;   // cos(angle) = re/|z|
  }
  if (store) {
    out[ob + k] = logf(mag + 1e-9f);
    out[ob + 2 * NBINS + k] = sv;
    out[ob + 3 * NBINS + k] = cv;
  }
  // hann spectrum via 3-tap stencil; X[-1] = conj(X[1])
  float2 zm, zp;
  if (k == 0) { float2 s1 = S[SWZ(off + 1)]; zm = make_float2(s1.x, -s1.y); }
  else zm = S[SWZ(off + k - 1)];
  zp = S[SWZ(off + k + 1)];
  float hr = 0.5f * z.x - 0.25f * (zm.x + zp.x);
  float hi = 0.5f * z.y - 0.25f * (zm.y + zp.y);
  mspec[k] = hr * hr + hi * hi;
}

// ---------- 4 frames per block: 2 complex FFTs, radix-4 (fused 2x radix-2) ----------
__global__ __launch_bounds__(256) void k_fft(
    const float* __restrict__ audio, const float* __restrict__ fb,
    const int* __restrict__ lohi, const float2* __restrict__ twg,
    float* __restrict__ out, int T, int nframes) {
  __shared__ float2 bufA[2][520];
  __shared__ float2 bufB[2][520];
  __shared__ float2 twL[NFFT];
  __shared__ float mspec[4][NBINS];

  const int t = threadIdx.x;
  const int ff = t >> 7;       // which FFT (0/1)
  const int v = t & 127;       // butterfly index within FFT
  const int frb = blockIdx.x * 4;
  const int fr0 = frb + 2 * ff;
  const int fr1 = fr0 + 1;
  const bool h0 = fr0 < nframes;
  const bool h1 = fr1 < nframes;

  for (int i = t; i < NFFT; i += 256) twL[i] = twg[i];

  float2* __restrict__ xa = bufA[ff];
  float2* __restrict__ xb = bufB[ff];

  // load packed frame pair with reflect padding: z = frame0 + i*frame1
  int s0 = fr0 * HOP - NFFT / 2;
  for (int i = v; i < NFFT; i += 128) {
    int q0 = s0 + i;
    if (q0 < 0) q0 = -q0;
    if (q0 >= T) q0 = 2 * T - 2 - q0;
    int q1 = s0 + HOP + i;
    if (q1 < 0) q1 = -q1;
    if (q1 >= T) q1 = 2 * T - 2 - q1;
    xa[SWZ(i)] = make_float2(audio[q0], h1 ? audio[q1] : 0.0f);
  }
  __syncthreads();

  float2 *x = xa, *y = xb;
#pragma unroll
  for (int ds = 0; ds < 4; ++ds) {
    const int m = 1 << (2 * ds);
    int qm = v & ~(m - 1);
    int r = v - qm;
    int o = 4 * qm + r;
    float2 x0 = x[SWZ(v)], x1 = x[SWZ(v + 128)], x2 = x[SWZ(v + 256)], x3 = x[SWZ(v + 384)];
    float2 s02 = make_float2(x0.x + x2.x, x0.y + x2.y);
    float2 d02 = make_float2(x0.x - x2.x, x0.y - x2.y);
    float2 s13 = make_float2(x1.x + x3.x, x1.y + x3.y);
    float2 d13 = make_float2(x1.x - x3.x, x1.y - x3.y);
    float2 E0 = make_float2(s02.x + s13.x, s02.y + s13.y);
    float2 u1 = make_float2(d02.x + d13.y, d02.y - d13.x);  // d02 - i*d13
    float2 u2 = make_float2(s02.x - s13.x, s02.y - s13.y);
    float2 u3 = make_float2(d02.x - d13.y, d02.y + d13.x);  // d02 + i*d13
    float2 E1 = cmul(twL[qm], u1);
    float2 E2 = cmul(twL[2 * qm], u2);
    float2 E3 = cmul(twL[3 * qm], u3);
    y[SWZ(o)] = E0;
    y[SWZ(o + m)] = E1;
    y[SWZ(o + 2 * m)] = E2;
    y[SWZ(o + 3 * m)] = E3;
    __syncthreads();
    float2* tmp = x; x = y; y = tmp;
  }
  // final radix-2 stage (m=256, twiddle=1)
#pragma unroll
  for (int j = 0; j < 2; ++j) {
    int b = v + 128 * j;
    float2 c0 = x[SWZ(b)], c1 = x[SWZ(b + 256)];
    y[SWZ(b)] = make_float2(c0.x + c1.x, c0.y + c1.y);
    y[SWZ(b + 256)] = make_float2(c0.x - c1.x, c0.y - c1.y);
  }
  __syncthreads();

  // unpack into x: X1 (frame fr0) at [0..257], X2 (fr1) at [258..515]
  for (int k = v; k < 258; k += 128) {
    int m2 = (NFFT - k) & (NFFT - 1);
    float2 Zk = y[SWZ(k)], Zm = y[SWZ(m2)];
    x[SWZ(k)] = make_float2(0.5f * (Zk.x + Zm.x), 0.5f * (Zk.y - Zm.y));
    x[SWZ(258 + k)] = make_float2(0.5f * (Zk.y + Zm.y), 0.5f * (Zm.x - Zk.x));
  }
  __syncthreads();

  unsigned ob0 = (unsigned)fr0 * ROW;
  unsigned ob1 = (unsigned)fr1 * ROW;
  for (int k = v; k < NBINS; k += 128) {
    epilogue_bin(x, 0, mspec[2 * ff], out, ob0, k, h0);
    epilogue_bin(x, 258, mspec[2 * ff + 1], out, ob1, k, h1);
  }
  __syncthreads();

  // sparse mel for both frames of this FFT
  for (int m = v; m < NBINS; m += 128) {
    int lo = lohi[m], hi = lohi[NBINS + m];
    float a0 = 0.0f, a1 = 0.0f;
    for (int f = lo; f <= hi; ++f) {
      float w = fb[f * NBINS + m];
      a0 = fmaf(mspec[2 * ff][f], w, a0);
      a1 = fmaf(mspec[2 * ff + 1][f], w, a1);
    }
    if (h0) out[ob0 + NBINS + m] = a0;
    if (h1) out[ob1 + NBINS + m] = a1;
  }
}

// ---------- pcen phase A: local chunk scan from zero -> mend ----------
__global__ __launch_bounds__(320) void k_pcen_a(const float* __restrict__ out,
                                                float* __restrict__ mend, int nframes) {
  int m = threadIdx.x;
  if (m >= NBINS) return;
  int c = blockIdx.x;
  int F0 = c * CHUNK;
  int end = min(F0 + CHUNK, nframes);
  const float SS = 0.025f, OMS = 1.0f - SS;
  float mm = 0.0f;
  int tf = F0;
  for (; tf + 16 <= end; tf += 16) {
    float xs[16];
#pragma unroll
    for (int j = 0; j < 16; ++j) xs[j] = out[(unsigned)(tf + j) * ROW + NBINS + m];
#pragma unroll
    for (int j = 0; j < 16; ++j) mm = OMS * mm + SS * xs[j];
  }
  for (; tf < end; ++tf) mm = OMS * mm + SS * out[(unsigned)tf * ROW + NBINS + m];
  mend[c * NBINS + m] = mm;
}

// ---------- pcen phase B: exact cross-chunk scan ----------
// Was: 292 serial iterations, one un-pipelined L2 load each (~450cy) = ~55us.
// Now: 16-deep load batches (addresses static/independent); identical FP
// order per column -> bit-identical result.
__global__ void k_pcen_b(const float* __restrict__ mend, float* __restrict__ vinit,
                         int chunks) {
  int m = threadIdx.x;
  if (m >= NBINS) return;
  float v = 0.0f;
  vinit[m] = 0.0f;
  int c = 1;
  for (; c + 16 <= chunks; c += 16) {
    float xs[16];
#pragma unroll
    for (int j = 0; j < 16; ++j) xs[j] = mend[(c - 1 + j) * NBINS + m];
#pragma unroll
    for (int j = 0; j < 16; ++j) {
      v = xs[j] + LAM128 * v;
      vinit[(c + j) * NBINS + m] = v;
    }
  }
  for (; c < chunks; ++c) {
    v = mend[(c - 1) * NBINS + m] + LAM128 * v;
    vinit[c * NBINS + m] = v;
  }
}

// ---------- pcen phase C: apply with exact init ----------
__global__ __launch_bounds__(320) void k_pcen_c(float* __restrict__ out,
                                                const float* __restrict__ vinit,
                                                int nframes) {
  int m = threadIdx.x;
  if (m >= NBINS) return;
  int c = blockIdx.x;
  int F0 = c * CHUNK;
  int end = min(F0 + CHUNK, nframes);
  const float SS = 0.025f, OMS = 1.0f - SS;
  const float SQ2 = sqrtf(2.0f);
  float mm = vinit[c * NBINS + m];
  int tf = F0;
  for (; tf + 16 <= end; tf += 16) {
    float xs[16], ys[16];
#pragma unroll
    for (int j = 0; j < 16; ++j) xs[j] = out[(unsigned)(tf + j) * ROW + NBINS + m];
#pragma unroll
    for (int j = 0; j < 16; ++j) {
      mm = OMS * mm + SS * xs[j];
      float den = expf(0.98f * logf(mm + 1e-6f));
      ys[j] = sqrtf(xs[j] / den + 2.0f) - SQ2;
    }
#pragma unroll
    for (int j = 0; j < 16; ++j) out[(unsigned)(tf + j) * ROW + NBINS + m] = ys[j];
  }
  for (; tf < end; ++tf) {
    unsigned idx = (unsigned)tf * ROW + NBINS + m;
    float xv = out[idx];
    mm = OMS * mm + SS * xv;
    float den = expf(0.98f * logf(mm + 1e-6f));
    out[idx] = sqrtf(xv / den + 2.0f) - SQ2;
  }
}

// ---------- column sum-of-squares partials (float4, deterministic) ----------
// Frame stride 1028 floats = 4112 B (16B-aligned) -> row = 257 float4s.
// Per-column accumulation order identical to scalar version -> bit-identical.
__global__ __launch_bounds__(256) void k_sumsq(const float* __restrict__ out,
                                               float* __restrict__ part,
                                               int nframes, int nblk) {
  int b = blockIdx.x, t = threadIdx.x;
  int per = (nframes + nblk - 1) / nblk;
  int f0 = b * per;
  int f1 = min(f0 + per, nframes);
  const float4* __restrict__ out4 = (const float4*)out;
  float4 acc = make_float4(0.f, 0.f, 0.f, 0.f);
  float4 accE = make_float4(0.f, 0.f, 0.f, 0.f);   // tail float4 (cols 1024..1027), t==0 only
  int f = f0;
  for (; f + 2 <= f1; f += 2) {
    unsigned ba = (unsigned)f * 257, bb = ba + 257;
    float4 va = out4[ba + t];
    float4 vb = out4[bb + t];
    float4 ea, eb;
    if (t == 0) { ea = out4[ba + 256]; eb = out4[bb + 256]; }
    acc.x = fmaf(va.x, va.x, acc.x); acc.y = fmaf(va.y, va.y, acc.y);
    acc.z = fmaf(va.z, va.z, acc.z); acc.w = fmaf(va.w, va.w, acc.w);
    acc.x = fmaf(vb.x, vb.x, acc.x); acc.y = fmaf(vb.y, vb.y, acc.y);
    acc.z = fmaf(vb.z, vb.z, acc.z); acc.w = fmaf(vb.w, vb.w, acc.w);
    if (t == 0) {
      accE.x = fmaf(ea.x, ea.x, accE.x); accE.y = fmaf(ea.y, ea.y, accE.y);
      accE.z = fmaf(ea.z, ea.z, accE.z); accE.w = fmaf(ea.w, ea.w, accE.w);
      accE.x = fmaf(eb.x, eb.x, accE.x); accE.y = fmaf(eb.y, eb.y, accE.y);
      accE.z = fmaf(eb.z, eb.z, accE.z); accE.w = fmaf(eb.w, eb.w, accE.w);
    }
  }
  for (; f < f1; ++f) {
    unsigned ba = (unsigned)f * 257;
    float4 va = out4[ba + t];
    acc.x = fmaf(va.x, va.x, acc.x); acc.y = fmaf(va.y, va.y, acc.y);
    acc.z = fmaf(va.z, va.z, acc.z); acc.w = fmaf(va.w, va.w, acc.w);
    if (t == 0) {
      float4 ea = out4[ba + 256];
      accE.x = fmaf(ea.x, ea.x, accE.x); accE.y = fmaf(ea.y, ea.y, accE.y);
      accE.z = fmaf(ea.z, ea.z, accE.z); accE.w = fmaf(ea.w, ea.w, accE.w);
    }
  }
  float4* part4 = (float4*)(part + (unsigned)b * ROW);
  part4[t] = acc;
  if (t == 0) part4[256] = accE;
}

// ---------- finalize norms: one block per column, LDS tree (deterministic) ----------
__global__ __launch_bounds__(256) void k_norm(const float* __restrict__ part,
                                              float* __restrict__ invn, int nblk) {
  __shared__ float red[256];
  int c = blockIdx.x, t = threadIdx.x;
  float s = 0.0f;
  for (int b = t; b < nblk; b += 256) s += part[(unsigned)b * ROW + c];
  red[t] = s;
  __syncthreads();
  for (int o = 128; o > 0; o >>= 1) {
    if (t < o) red[t] += red[t + o];
    __syncthreads();
  }
  if (t == 0) invn[c] = 1.0f / fmaxf(sqrtf(red[0]), 1e-12f);
}

// ---------- scale pass ----------
__global__ __launch_bounds__(256) void k_scale(float4* __restrict__ out4,
                                               const float* __restrict__ invn,
                                               long n4) {
  __shared__ float inv[ROW];
  for (int i = threadIdx.x; i < ROW; i += 256) inv[i] = invn[i];
  __syncthreads();
  long stride = (long)gridDim.x * 256;
  for (long i = (long)blockIdx.x * 256 + threadIdx.x; i < n4; i += stride) {
    float4 v = out4[i];
    int col = (int)((i * 4) % ROW);
    v.x *= inv[col];
    v.y *= inv[col + 1];
    v.z *= inv[col + 2];
    v.w *= inv[col + 3];
    out4[i] = v;
  }
}

extern "C" void kernel_launch(void* const* d_in, const int* in_sizes, int n_in,
                              void* d_out, int out_size, void* d_ws, size_t ws_size,
                              hipStream_t stream) {
  const float* audio = (const float*)d_in[0];
  const float* fb = (const float*)d_in[1];
  int T = in_sizes[0];
  int nframes = 1 + T / HOP;  // center=True, pad = NFFT/2 both sides
  float* out = (float*)d_out;
  int chunks = (nframes + CHUNK - 1) / CHUNK;

  // ws layout (floats): twg[1024] | mend[chunks*257] | vinit[chunks*257] |
  //                     invn[1028] | lohi[514](int) | pad | part[nblk*1028]
  float* wsf = (float*)d_ws;
  float2* twg = (float2*)wsf;
  float* mend = wsf + 1024;
  float* vinit = mend + (long)chunks * NBINS;
  float* invn = vinit + (long)chunks * NBINS;
  int* lohi = (int*)(invn + ROW);
  long base = 1024 + 2L * chunks * NBINS + ROW + 2 * NBINS;
  base = (base + 3) & ~3L;   // 16B-align part for float4 stores
  float* part = wsf + base;
  long avail = (long)(ws_size / 4) - base - 64;
  int nblk = 1024;
  while (nblk > 64 && (long)nblk * ROW > avail) nblk >>= 1;

  k_prep<<<1, 256, 0, stream>>>(fb, lohi, twg);
  k_fft<<<(nframes + 3) / 4, 256, 0, stream>>>(audio, fb, lohi, twg, out, T, nframes);
  k_pcen_a<<<chunks, 320, 0, stream>>>(out, mend, nframes);
  k_pcen_b<<<1, 320, 0, stream>>>(mend, vinit, chunks);
  k_pcen_c<<<chunks, 320, 0, stream>>>(out, vinit, nframes);
  k_sumsq<<<nblk, 256, 0, stream>>>(out, part, nframes, nblk);
  k_norm<<<ROW, 256, 0, stream>>>(part, invn, nblk);
  long n4 = (long)nframes * ROW / 4;
  k_scale<<<2048, 256, 0, stream>>>((float4*)out, invn, n4);
}

// Round 9
// 248.083 us; speedup vs baseline: 1.2736x; 1.0191x over previous
//
#include <hip/hip_runtime.h>
#include <math.h>

#define NFFT 512
#define HOP 128
#define NBINS 257
#define ROW 1028          // 4*257
#define CHUNK 128
#define LAM128 0.0391373f // 0.975^128 (exact cross-chunk decay)
// LDS swizzle for FFT buffers: bijective, applied to EVERY access.
#define SWZ(a) ((a) ^ (((a) >> 4) & 15))

__device__ __forceinline__ float2 cmul(float2 a, float2 b) {
  return make_float2(a.x * b.x - a.y * b.y, a.x * b.y + a.y * b.x);
}

// ---------- prep: twiddle table (once) + sparse filterbank spans ----------
__global__ void k_prep(const float* __restrict__ fb, int* __restrict__ lohi,
                       float2* __restrict__ twg) {
  int t = threadIdx.x;
  for (int i = t; i < NFFT; i += 256) {
    double ang = -6.283185307179586476925286766559 * (double)i / (double)NFFT;
    twg[i] = make_float2((float)cos(ang), (float)sin(ang));
  }
  for (int m = t; m < NBINS; m += 256) {
    int lo = 0, hi = -1;
    for (int f = 0; f < NBINS; ++f) {
      if (fb[f * NBINS + m] != 0.0f) { if (hi < 0) lo = f; hi = f; }
    }
    lohi[m] = lo;
    lohi[NBINS + m] = hi;
  }
}

// ---------- per-bin epilogue (S = swizzled LDS array, off = subarray base) ----------
__device__ __forceinline__ void epilogue_bin(const float2* __restrict__ S, int off,
                                             float* __restrict__ mspec,
                                             float* __restrict__ out, unsigned ob,
                                             int k, bool store) {
  float2 z = S[SWZ(off + k)];
  float mag, sv, cv;
  if (k == 0 || k == 256) {
    // z.y is EXACTLY 0 here (unpack cancels identically at k==m). The f32
    // reference computes sin(atan2(+0, re)) = sin(pi_f32) = -8.742278e-8 when
    // re<0 — NOT 0. F.normalize scales that column to -1/sqrt(N_neg), so we
    // must emit the same tiny values for the norm to match.
    mag = fabsf(z.x);
    sv = sinf(atan2f(0.0f, z.x));
    cv = copysignf(1.0f, z.x);
  } else {
    mag = sqrtf(z.x * z.x + z.y * z.y);
    float inv = (mag > 0.0f) ? 1.0f / mag : 0.0f;
    sv = (mag > 0.0f) ? z.y * inv : 0.0f;   // sin(angle) = im/|z|
    cv = (mag > 0.0f) ? z.x * inv : 1.0f;   // cos(angle) = re/|z|
  }
  if (store) {
    out[ob + k] = __logf(mag + 1e-9f);   // hw log: ~1ulp, ~5e-9 after norm
    out[ob + 2 * NBINS + k] = sv;
    out[ob + 3 * NBINS + k] = cv;
  }
  // hann spectrum via 3-tap stencil; X[-1] = conj(X[1])
  float2 zm, zp;
  if (k == 0) { float2 s1 = S[SWZ(off + 1)]; zm = make_float2(s1.x, -s1.y); }
  else zm = S[SWZ(off + k - 1)];
  zp = S[SWZ(off + k + 1)];
  float hr = 0.5f * z.x - 0.25f * (zm.x + zp.x);
  float hi = 0.5f * z.y - 0.25f * (zm.y + zp.y);
  mspec[k] = hr * hr + hi * hi;
}

// ---------- 4 frames per block: 2 complex FFTs, radix-4 (fused 2x radix-2) ----------
__global__ __launch_bounds__(256) void k_fft(
    const float* __restrict__ audio, const float* __restrict__ fb,
    const int* __restrict__ lohi, const float2* __restrict__ twg,
    float* __restrict__ out, int T, int nframes) {
  __shared__ float2 bufA[2][520];
  __shared__ float2 bufB[2][520];
  __shared__ float2 twL[NFFT];
  __shared__ float mspec[4][NBINS];

  const int t = threadIdx.x;
  const int ff = t >> 7;       // which FFT (0/1)
  const int v = t & 127;       // butterfly index within FFT
  const int frb = blockIdx.x * 4;
  const int fr0 = frb + 2 * ff;
  const int fr1 = fr0 + 1;
  const bool h0 = fr0 < nframes;
  const bool h1 = fr1 < nframes;

  for (int i = t; i < NFFT; i += 256) twL[i] = twg[i];

  float2* __restrict__ xa = bufA[ff];
  float2* __restrict__ xb = bufB[ff];

  // load packed frame pair with reflect padding: z = frame0 + i*frame1
  int s0 = fr0 * HOP - NFFT / 2;
  for (int i = v; i < NFFT; i += 128) {
    int q0 = s0 + i;
    if (q0 < 0) q0 = -q0;
    if (q0 >= T) q0 = 2 * T - 2 - q0;
    int q1 = s0 + HOP + i;
    if (q1 < 0) q1 = -q1;
    if (q1 >= T) q1 = 2 * T - 2 - q1;
    xa[SWZ(i)] = make_float2(audio[q0], h1 ? audio[q1] : 0.0f);
  }
  __syncthreads();

  float2 *x = xa, *y = xb;
#pragma unroll
  for (int ds = 0; ds < 4; ++ds) {
    const int m = 1 << (2 * ds);
    int qm = v & ~(m - 1);
    int r = v - qm;
    int o = 4 * qm + r;
    float2 x0 = x[SWZ(v)], x1 = x[SWZ(v + 128)], x2 = x[SWZ(v + 256)], x3 = x[SWZ(v + 384)];
    float2 s02 = make_float2(x0.x + x2.x, x0.y + x2.y);
    float2 d02 = make_float2(x0.x - x2.x, x0.y - x2.y);
    float2 s13 = make_float2(x1.x + x3.x, x1.y + x3.y);
    float2 d13 = make_float2(x1.x - x3.x, x1.y - x3.y);
    float2 E0 = make_float2(s02.x + s13.x, s02.y + s13.y);
    float2 u1 = make_float2(d02.x + d13.y, d02.y - d13.x);  // d02 - i*d13
    float2 u2 = make_float2(s02.x - s13.x, s02.y - s13.y);
    float2 u3 = make_float2(d02.x - d13.y, d02.y + d13.x);  // d02 + i*d13
    float2 E1 = cmul(twL[qm], u1);
    float2 E2 = cmul(twL[2 * qm], u2);
    float2 E3 = cmul(twL[3 * qm], u3);
    y[SWZ(o)] = E0;
    y[SWZ(o + m)] = E1;
    y[SWZ(o + 2 * m)] = E2;
    y[SWZ(o + 3 * m)] = E3;
    __syncthreads();
    float2* tmp = x; x = y; y = tmp;
  }
  // After 4 swaps: x == bufA (stage-3 output), y == bufB (free).
  // Final radix-2 is twiddle-free: Z[k]=x[k]+x[k+256], Z[k+256]=x[k]-x[k+256].
  // Fuse it into the unpack: reconstruct Zk, Z(512-k) straight from x,
  // skipping one full 512-pt LDS round-trip + barrier.
  for (int k = v; k < 258; k += 128) {
    float2 Zk, Zm;
    if (k <= 255) {
      float2 a0 = x[SWZ(k)], a1 = x[SWZ(k + 256)];
      Zk = make_float2(a0.x + a1.x, a0.y + a1.y);
    } else {
      float2 a0 = x[SWZ(k - 256)], a1 = x[SWZ(k)];
      Zk = make_float2(a0.x - a1.x, a0.y - a1.y);
    }
    int m2 = (NFFT - k) & (NFFT - 1);
    if (k == 0 || k == 256) {
      Zm = Zk;                       // structural: X1.im = X2.im = 0 exactly
    } else if (m2 >= 256) {          // k in 1..255
      float2 b0 = x[SWZ(m2 - 256)], b1 = x[SWZ(m2)];
      Zm = make_float2(b0.x - b1.x, b0.y - b1.y);
    } else {                         // k == 257 -> m2 = 255
      float2 b0 = x[SWZ(m2)], b1 = x[SWZ(m2 + 256)];
      Zm = make_float2(b0.x + b1.x, b0.y + b1.y);
    }
    y[SWZ(k)] = make_float2(0.5f * (Zk.x + Zm.x), 0.5f * (Zk.y - Zm.y));
    y[SWZ(258 + k)] = make_float2(0.5f * (Zk.y + Zm.y), 0.5f * (Zm.x - Zk.x));
  }
  __syncthreads();

  unsigned ob0 = (unsigned)fr0 * ROW;
  unsigned ob1 = (unsigned)fr1 * ROW;
  for (int k = v; k < NBINS; k += 128) {
    epilogue_bin(y, 0, mspec[2 * ff], out, ob0, k, h0);
    epilogue_bin(y, 258, mspec[2 * ff + 1], out, ob1, k, h1);
  }
  __syncthreads();

  // sparse mel for both frames of this FFT
  for (int m = v; m < NBINS; m += 128) {
    int lo = lohi[m], hi = lohi[NBINS + m];
    float a0 = 0.0f, a1 = 0.0f;
    for (int f = lo; f <= hi; ++f) {
      float w = fb[f * NBINS + m];
      a0 = fmaf(mspec[2 * ff][f], w, a0);
      a1 = fmaf(mspec[2 * ff + 1][f], w, a1);
    }
    if (h0) out[ob0 + NBINS + m] = a0;
    if (h1) out[ob1 + NBINS + m] = a1;
  }
}

// ---------- pcen phase A: local chunk scan from zero -> mend ----------
__global__ __launch_bounds__(320) void k_pcen_a(const float* __restrict__ out,
                                                float* __restrict__ mend, int nframes) {
  int m = threadIdx.x;
  if (m >= NBINS) return;
  int c = blockIdx.x;
  int F0 = c * CHUNK;
  int end = min(F0 + CHUNK, nframes);
  const float SS = 0.025f, OMS = 1.0f - SS;
  float mm = 0.0f;
  int tf = F0;
  for (; tf + 16 <= end; tf += 16) {
    float xs[16];
#pragma unroll
    for (int j = 0; j < 16; ++j) xs[j] = out[(unsigned)(tf + j) * ROW + NBINS + m];
#pragma unroll
    for (int j = 0; j < 16; ++j) mm = OMS * mm + SS * xs[j];
  }
  for (; tf < end; ++tf) mm = OMS * mm + SS * out[(unsigned)tf * ROW + NBINS + m];
  mend[c * NBINS + m] = mm;
}

// ---------- pcen phase B: exact cross-chunk scan (batched loads) ----------
__global__ void k_pcen_b(const float* __restrict__ mend, float* __restrict__ vinit,
                         int chunks) {
  int m = threadIdx.x;
  if (m >= NBINS) return;
  float v = 0.0f;
  vinit[m] = 0.0f;
  int c = 1;
  for (; c + 16 <= chunks; c += 16) {
    float xs[16];
#pragma unroll
    for (int j = 0; j < 16; ++j) xs[j] = mend[(c - 1 + j) * NBINS + m];
#pragma unroll
    for (int j = 0; j < 16; ++j) {
      v = xs[j] + LAM128 * v;
      vinit[(c + j) * NBINS + m] = v;
    }
  }
  for (; c < chunks; ++c) {
    v = mend[(c - 1) * NBINS + m] + LAM128 * v;
    vinit[c * NBINS + m] = v;
  }
}

// ---------- pcen phase C: apply with exact init ----------
__global__ __launch_bounds__(320) void k_pcen_c(float* __restrict__ out,
                                                const float* __restrict__ vinit,
                                                int nframes) {
  int m = threadIdx.x;
  if (m >= NBINS) return;
  int c = blockIdx.x;
  int F0 = c * CHUNK;
  int end = min(F0 + CHUNK, nframes);
  const float SS = 0.025f, OMS = 1.0f - SS;
  const float SQ2 = sqrtf(2.0f);
  float mm = vinit[c * NBINS + m];
  int tf = F0;
  for (; tf + 16 <= end; tf += 16) {
    float xs[16], ys[16];
#pragma unroll
    for (int j = 0; j < 16; ++j) xs[j] = out[(unsigned)(tf + j) * ROW + NBINS + m];
#pragma unroll
    for (int j = 0; j < 16; ++j) {
      mm = OMS * mm + SS * xs[j];
      float den = __expf(0.98f * __logf(mm + 1e-6f));
      ys[j] = sqrtf(xs[j] / den + 2.0f) - SQ2;
    }
#pragma unroll
    for (int j = 0; j < 16; ++j) out[(unsigned)(tf + j) * ROW + NBINS + m] = ys[j];
  }
  for (; tf < end; ++tf) {
    unsigned idx = (unsigned)tf * ROW + NBINS + m;
    float xv = out[idx];
    mm = OMS * mm + SS * xv;
    float den = __expf(0.98f * __logf(mm + 1e-6f));
    out[idx] = sqrtf(xv / den + 2.0f) - SQ2;
  }
}

// ---------- column sum-of-squares partials (float4, deterministic) ----------
__global__ __launch_bounds__(256) void k_sumsq(const float* __restrict__ out,
                                               float* __restrict__ part,
                                               int nframes, int nblk) {
  int b = blockIdx.x, t = threadIdx.x;
  int per = (nframes + nblk - 1) / nblk;
  int f0 = b * per;
  int f1 = min(f0 + per, nframes);
  const float4* __restrict__ out4 = (const float4*)out;
  float4 acc = make_float4(0.f, 0.f, 0.f, 0.f);
  float4 accE = make_float4(0.f, 0.f, 0.f, 0.f);
  int f = f0;
  for (; f + 2 <= f1; f += 2) {
    unsigned ba = (unsigned)f * 257, bb = ba + 257;
    float4 va = out4[ba + t];
    float4 vb = out4[bb + t];
    float4 ea, eb;
    if (t == 0) { ea = out4[ba + 256]; eb = out4[bb + 256]; }
    acc.x = fmaf(va.x, va.x, acc.x); acc.y = fmaf(va.y, va.y, acc.y);
    acc.z = fmaf(va.z, va.z, acc.z); acc.w = fmaf(va.w, va.w, acc.w);
    acc.x = fmaf(vb.x, vb.x, acc.x); acc.y = fmaf(vb.y, vb.y, acc.y);
    acc.z = fmaf(vb.z, vb.z, acc.z); acc.w = fmaf(vb.w, vb.w, acc.w);
    if (t == 0) {
      accE.x = fmaf(ea.x, ea.x, accE.x); accE.y = fmaf(ea.y, ea.y, accE.y);
      accE.z = fmaf(ea.z, ea.z, accE.z); accE.w = fmaf(ea.w, ea.w, accE.w);
      accE.x = fmaf(eb.x, eb.x, accE.x); accE.y = fmaf(eb.y, eb.y, accE.y);
      accE.z = fmaf(eb.z, eb.z, accE.z); accE.w = fmaf(eb.w, eb.w, accE.w);
    }
  }
  for (; f < f1; ++f) {
    unsigned ba = (unsigned)f * 257;
    float4 va = out4[ba + t];
    acc.x = fmaf(va.x, va.x, acc.x); acc.y = fmaf(va.y, va.y, acc.y);
    acc.z = fmaf(va.z, va.z, acc.z); acc.w = fmaf(va.w, va.w, acc.w);
    if (t == 0) {
      float4 ea = out4[ba + 256];
      accE.x = fmaf(ea.x, ea.x, accE.x); accE.y = fmaf(ea.y, ea.y, accE.y);
      accE.z = fmaf(ea.z, ea.z, accE.z); accE.w = fmaf(ea.w, ea.w, accE.w);
    }
  }
  float4* part4 = (float4*)(part + (unsigned)b * ROW);
  part4[t] = acc;
  if (t == 0) part4[256] = accE;
}

// ---------- finalize norms: one block per column, LDS tree (deterministic) ----------
__global__ __launch_bounds__(256) void k_norm(const float* __restrict__ part,
                                              float* __restrict__ invn, int nblk) {
  __shared__ float red[256];
  int c = blockIdx.x, t = threadIdx.x;
  float s = 0.0f;
  for (int b = t; b < nblk; b += 256) s += part[(unsigned)b * ROW + c];
  red[t] = s;
  __syncthreads();
  for (int o = 128; o > 0; o >>= 1) {
    if (t < o) red[t] += red[t + o];
    __syncthreads();
  }
  if (t == 0) invn[c] = 1.0f / fmaxf(sqrtf(red[0]), 1e-12f);
}

// ---------- scale pass ----------
__global__ __launch_bounds__(256) void k_scale(float4* __restrict__ out4,
                                               const float* __restrict__ invn,
                                               long n4) {
  __shared__ float inv[ROW];
  for (int i = threadIdx.x; i < ROW; i += 256) inv[i] = invn[i];
  __syncthreads();
  long stride = (long)gridDim.x * 256;
  for (long i = (long)blockIdx.x * 256 + threadIdx.x; i < n4; i += stride) {
    float4 v = out4[i];
    int col = (int)((i * 4) % ROW);
    v.x *= inv[col];
    v.y *= inv[col + 1];
    v.z *= inv[col + 2];
    v.w *= inv[col + 3];
    out4[i] = v;
  }
}

extern "C" void kernel_launch(void* const* d_in, const int* in_sizes, int n_in,
                              void* d_out, int out_size, void* d_ws, size_t ws_size,
                              hipStream_t stream) {
  const float* audio = (const float*)d_in[0];
  const float* fb = (const float*)d_in[1];
  int T = in_sizes[0];
  int nframes = 1 + T / HOP;  // center=True, pad = NFFT/2 both sides
  float* out = (float*)d_out;
  int chunks = (nframes + CHUNK - 1) / CHUNK;

  // ws layout (floats): twg[1024] | mend[chunks*257] | vinit[chunks*257] |
  //                     invn[1028] | lohi[514](int) | pad | part[nblk*1028]
  float* wsf = (float*)d_ws;
  float2* twg = (float2*)wsf;
  float* mend = wsf + 1024;
  float* vinit = mend + (long)chunks * NBINS;
  float* invn = vinit + (long)chunks * NBINS;
  int* lohi = (int*)(invn + ROW);
  long base = 1024 + 2L * chunks * NBINS + ROW + 2 * NBINS;
  base = (base + 3) & ~3L;   // 16B-align part for float4 stores
  float* part = wsf + base;
  long avail = (long)(ws_size / 4) - base - 64;
  int nblk = 1024;
  while (nblk > 64 && (long)nblk * ROW > avail) nblk >>= 1;

  k_prep<<<1, 256, 0, stream>>>(fb, lohi, twg);
  k_fft<<<(nframes + 3) / 4, 256, 0, stream>>>(audio, fb, lohi, twg, out, T, nframes);
  k_pcen_a<<<chunks, 320, 0, stream>>>(out, mend, nframes);
  k_pcen_b<<<1, 320, 0, stream>>>(mend, vinit, chunks);
  k_pcen_c<<<chunks, 320, 0, stream>>>(out, vinit, nframes);
  k_sumsq<<<nblk, 256, 0, stream>>>(out, part, nframes, nblk);
  k_norm<<<ROW, 256, 0, stream>>>(part, invn, nblk);
  long n4 = (long)nframes * ROW / 4;
  k_scale<<<2048, 256, 0, stream>>>((float4*)out, invn, n4);
}

// Round 10
// 229.709 us; speedup vs baseline: 1.3755x; 1.0800x over previous
//
#include <hip/hip_runtime.h>
#include <math.h>

#define NFFT 512
#define HOP 128
#define NBINS 257
#define ROW 1028          // 4*257
#define CHUNK 64
#define LAM64 0.19783147f // 0.975^64 (verified: LAM64^2 == old LAM128 0.0391373)
// LDS swizzle for FFT buffers: bijective, applied to EVERY access.
#define SWZ(a) ((a) ^ (((a) >> 4) & 15))

__device__ __forceinline__ float2 cmul(float2 a, float2 b) {
  return make_float2(a.x * b.x - a.y * b.y, a.x * b.y + a.y * b.x);
}

// ---------- prep: twiddle table (once) + sparse filterbank spans ----------
__global__ void k_prep(const float* __restrict__ fb, int* __restrict__ lohi,
                       float2* __restrict__ twg) {
  int t = threadIdx.x;
  for (int i = t; i < NFFT; i += 256) {
    double ang = -6.283185307179586476925286766559 * (double)i / (double)NFFT;
    twg[i] = make_float2((float)cos(ang), (float)sin(ang));
  }
  for (int m = t; m < NBINS; m += 256) {
    int lo = 0, hi = -1;
    for (int f = 0; f < NBINS; ++f) {
      if (fb[f * NBINS + m] != 0.0f) { if (hi < 0) lo = f; hi = f; }
    }
    lohi[m] = lo;
    lohi[NBINS + m] = hi;
  }
}

// ---------- per-bin epilogue (S = swizzled LDS array, off = subarray base) ----------
__device__ __forceinline__ void epilogue_bin(const float2* __restrict__ S, int off,
                                             float* __restrict__ mspec,
                                             float* __restrict__ out, unsigned ob,
                                             int k, bool store) {
  float2 z = S[SWZ(off + k)];
  float mag, sv, cv;
  if (k == 0 || k == 256) {
    // z.y is EXACTLY 0 here (unpack cancels identically at k==m). The f32
    // reference computes sin(atan2(+0, re)) = sin(pi_f32) = -8.742278e-8 when
    // re<0 — NOT 0. F.normalize scales that column to -1/sqrt(N_neg), so we
    // must emit the same tiny values for the norm to match.
    mag = fabsf(z.x);
    sv = sinf(atan2f(0.0f, z.x));
    cv = copysignf(1.0f, z.x);
  } else {
    // one hw rsq replaces precise sqrt + precise div (~20 instr -> ~6)
    float r2 = fmaf(z.x, z.x, z.y * z.y);
    if (r2 > 0.0f) {
      float rs = __builtin_amdgcn_rsqf(r2);
      mag = r2 * rs;            // sqrt(r2) to ~1ulp
      sv = z.y * rs;            // sin(angle) = im/|z|
      cv = z.x * rs;            // cos(angle) = re/|z|
    } else { mag = 0.0f; sv = 0.0f; cv = 1.0f; }
  }
  if (store) {
    out[ob + k] = __logf(mag + 1e-9f);
    out[ob + 2 * NBINS + k] = sv;
    out[ob + 3 * NBINS + k] = cv;
  }
  // hann spectrum via 3-tap stencil; X[-1] = conj(X[1])
  float2 zm, zp;
  if (k == 0) { float2 s1 = S[SWZ(off + 1)]; zm = make_float2(s1.x, -s1.y); }
  else zm = S[SWZ(off + k - 1)];
  zp = S[SWZ(off + k + 1)];
  float hr = 0.5f * z.x - 0.25f * (zm.x + zp.x);
  float hi = 0.5f * z.y - 0.25f * (zm.y + zp.y);
  mspec[k] = hr * hr + hi * hi;
}

// ---------- 4 frames per block: 2 complex FFTs, radix-4 (fused 2x radix-2) ----------
__global__ __launch_bounds__(256) void k_fft(
    const float* __restrict__ audio, const float* __restrict__ fb,
    const int* __restrict__ lohi, const float2* __restrict__ twg,
    float* __restrict__ out, int T, int nframes) {
  __shared__ float2 bufA[2][520];
  __shared__ float2 bufB[2][520];
  __shared__ float2 twL[NFFT];
  __shared__ float mspec[4][NBINS];

  const int t = threadIdx.x;
  const int ff = t >> 7;       // which FFT (0/1)
  const int v = t & 127;       // butterfly index within FFT
  const int frb = blockIdx.x * 4;
  const int fr0 = frb + 2 * ff;
  const int fr1 = fr0 + 1;
  const bool h0 = fr0 < nframes;
  const bool h1 = fr1 < nframes;

  for (int i = t; i < NFFT; i += 256) twL[i] = twg[i];

  float2* __restrict__ xa = bufA[ff];
  float2* __restrict__ xb = bufB[ff];

  // load packed frame pair with reflect padding: z = frame0 + i*frame1
  int s0 = fr0 * HOP - NFFT / 2;
  for (int i = v; i < NFFT; i += 128) {
    int q0 = s0 + i;
    if (q0 < 0) q0 = -q0;
    if (q0 >= T) q0 = 2 * T - 2 - q0;
    int q1 = s0 + HOP + i;
    if (q1 < 0) q1 = -q1;
    if (q1 >= T) q1 = 2 * T - 2 - q1;
    xa[SWZ(i)] = make_float2(audio[q0], h1 ? audio[q1] : 0.0f);
  }
  __syncthreads();

  float2 *x = xa, *y = xb;
#pragma unroll
  for (int ds = 0; ds < 4; ++ds) {
    const int m = 1 << (2 * ds);
    int qm = v & ~(m - 1);
    int r = v - qm;
    int o = 4 * qm + r;
    float2 x0 = x[SWZ(v)], x1 = x[SWZ(v + 128)], x2 = x[SWZ(v + 256)], x3 = x[SWZ(v + 384)];
    float2 s02 = make_float2(x0.x + x2.x, x0.y + x2.y);
    float2 d02 = make_float2(x0.x - x2.x, x0.y - x2.y);
    float2 s13 = make_float2(x1.x + x3.x, x1.y + x3.y);
    float2 d13 = make_float2(x1.x - x3.x, x1.y - x3.y);
    float2 E0 = make_float2(s02.x + s13.x, s02.y + s13.y);
    float2 u1 = make_float2(d02.x + d13.y, d02.y - d13.x);  // d02 - i*d13
    float2 u2 = make_float2(s02.x - s13.x, s02.y - s13.y);
    float2 u3 = make_float2(d02.x - d13.y, d02.y + d13.x);  // d02 + i*d13
    float2 E1 = cmul(twL[qm], u1);
    float2 E2 = cmul(twL[2 * qm], u2);
    float2 E3 = cmul(twL[3 * qm], u3);
    y[SWZ(o)] = E0;
    y[SWZ(o + m)] = E1;
    y[SWZ(o + 2 * m)] = E2;
    y[SWZ(o + 3 * m)] = E3;
    __syncthreads();
    float2* tmp = x; x = y; y = tmp;
  }
  // Final radix-2 is twiddle-free; fuse into the unpack (reconstruct Zk, Z512-k
  // directly from stage-3 output in x), skipping one LDS round-trip + barrier.
  for (int k = v; k < 258; k += 128) {
    float2 Zk, Zm;
    if (k <= 255) {
      float2 a0 = x[SWZ(k)], a1 = x[SWZ(k + 256)];
      Zk = make_float2(a0.x + a1.x, a0.y + a1.y);
    } else {
      float2 a0 = x[SWZ(k - 256)], a1 = x[SWZ(k)];
      Zk = make_float2(a0.x - a1.x, a0.y - a1.y);
    }
    int m2 = (NFFT - k) & (NFFT - 1);
    if (k == 0 || k == 256) {
      Zm = Zk;                       // structural: X1.im = X2.im = 0 exactly
    } else if (m2 >= 256) {          // k in 1..255
      float2 b0 = x[SWZ(m2 - 256)], b1 = x[SWZ(m2)];
      Zm = make_float2(b0.x - b1.x, b0.y - b1.y);
    } else {                         // k == 257 -> m2 = 255
      float2 b0 = x[SWZ(m2)], b1 = x[SWZ(m2 + 256)];
      Zm = make_float2(b0.x + b1.x, b0.y + b1.y);
    }
    y[SWZ(k)] = make_float2(0.5f * (Zk.x + Zm.x), 0.5f * (Zk.y - Zm.y));
    y[SWZ(258 + k)] = make_float2(0.5f * (Zk.y + Zm.y), 0.5f * (Zm.x - Zk.x));
  }
  __syncthreads();

  unsigned ob0 = (unsigned)fr0 * ROW;
  unsigned ob1 = (unsigned)fr1 * ROW;
  for (int k = v; k < NBINS; k += 128) {
    epilogue_bin(y, 0, mspec[2 * ff], out, ob0, k, h0);
    epilogue_bin(y, 258, mspec[2 * ff + 1], out, ob1, k, h1);
  }
  __syncthreads();

  // sparse mel for both frames of this FFT
  for (int m = v; m < NBINS; m += 128) {
    int lo = lohi[m], hi = lohi[NBINS + m];
    float a0 = 0.0f, a1 = 0.0f;
    for (int f = lo; f <= hi; ++f) {
      float w = fb[f * NBINS + m];
      a0 = fmaf(mspec[2 * ff][f], w, a0);
      a1 = fmaf(mspec[2 * ff + 1][f], w, a1);
    }
    if (h0) out[ob0 + NBINS + m] = a0;
    if (h1) out[ob1 + NBINS + m] = a1;
  }
}

// ---------- pcen phase A: local chunk scan from zero -> mend ----------
__global__ __launch_bounds__(320) void k_pcen_a(const float* __restrict__ out,
                                                float* __restrict__ mend, int nframes) {
  int m = threadIdx.x;
  if (m >= NBINS) return;
  int c = blockIdx.x;
  int F0 = c * CHUNK;
  int end = min(F0 + CHUNK, nframes);
  const float SS = 0.025f, OMS = 1.0f - SS;
  float mm = 0.0f;
  int tf = F0;
  for (; tf + 16 <= end; tf += 16) {
    float xs[16];
#pragma unroll
    for (int j = 0; j < 16; ++j) xs[j] = out[(unsigned)(tf + j) * ROW + NBINS + m];
#pragma unroll
    for (int j = 0; j < 16; ++j) mm = OMS * mm + SS * xs[j];
  }
  for (; tf < end; ++tf) mm = OMS * mm + SS * out[(unsigned)tf * ROW + NBINS + m];
  mend[c * NBINS + m] = mm;
}

// ---------- pcen phase B: exact cross-chunk scan (batched loads) ----------
__global__ void k_pcen_b(const float* __restrict__ mend, float* __restrict__ vinit,
                         int chunks) {
  int m = threadIdx.x;
  if (m >= NBINS) return;
  float v = 0.0f;
  vinit[m] = 0.0f;
  int c = 1;
  for (; c + 16 <= chunks; c += 16) {
    float xs[16];
#pragma unroll
    for (int j = 0; j < 16; ++j) xs[j] = mend[(c - 1 + j) * NBINS + m];
#pragma unroll
    for (int j = 0; j < 16; ++j) {
      v = xs[j] + LAM64 * v;
      vinit[(c + j) * NBINS + m] = v;
    }
  }
  for (; c < chunks; ++c) {
    v = mend[(c - 1) * NBINS + m] + LAM64 * v;
    vinit[c * NBINS + m] = v;
  }
}

// ---------- pcen phase C (fused with column sumsq) ----------
// Phase 1: scan+rewrite ch1; ch1 column squares accumulate FREE from registers.
// Phase 2: batched read of ch0/2/3 -> column sumsq partials for this chunk.
// Replaces the standalone k_sumsq pass (saves a full 154MB read + a launch).
__global__ __launch_bounds__(320) void k_pcen_c(float* __restrict__ out,
                                                const float* __restrict__ vinit,
                                                float* __restrict__ part,
                                                int nframes) {
  int t = threadIdx.x;
  int c = blockIdx.x;
  int F0 = c * CHUNK;
  int end = min(F0 + CHUNK, nframes);
  const float SS = 0.025f, OMS = 1.0f - SS;
  const float SQ2 = sqrtf(2.0f);
  float acc1 = 0.0f;
  if (t < NBINS) {
    int m = t;
    float mm = vinit[c * NBINS + m];
    int tf = F0;
    for (; tf + 16 <= end; tf += 16) {
      float xs[16], ys[16];
#pragma unroll
      for (int j = 0; j < 16; ++j) xs[j] = out[(unsigned)(tf + j) * ROW + NBINS + m];
#pragma unroll
      for (int j = 0; j < 16; ++j) {
        mm = OMS * mm + SS * xs[j];
        float invden = __expf(-0.98f * __logf(mm + 1e-6f));  // 1/den, no division
        float val = fmaf(xs[j], invden, 2.0f);
        float rs = __builtin_amdgcn_rsqf(val);
        ys[j] = val * rs - SQ2;   // sqrt(val) - sqrt(2), ~1ulp
        acc1 = fmaf(ys[j], ys[j], acc1);
      }
#pragma unroll
      for (int j = 0; j < 16; ++j) out[(unsigned)(tf + j) * ROW + NBINS + m] = ys[j];
    }
    for (; tf < end; ++tf) {
      unsigned idx = (unsigned)tf * ROW + NBINS + m;
      float xv = out[idx];
      mm = OMS * mm + SS * xv;
      float invden = __expf(-0.98f * __logf(mm + 1e-6f));
      float val = fmaf(xv, invden, 2.0f);
      float rs = __builtin_amdgcn_rsqf(val);
      float yv = val * rs - SQ2;
      acc1 = fmaf(yv, yv, acc1);
      out[idx] = yv;
    }
  }
  // phase 2: ch0 (cols 0..256) + ch2/3 (cols 514..1027) = 771 columns
  float acc2[3] = {0.f, 0.f, 0.f};
  int col[3]; bool cok[3];
#pragma unroll
  for (int g = 0; g < 3; ++g) {
    int i = t + 320 * g;
    cok[g] = i < 771;
    col[g] = (i < 257) ? i : i + 257;
    if (!cok[g]) col[g] = 0;
  }
  int f = F0;
  for (; f + 8 <= end; f += 8) {
    float xs[8][3];
#pragma unroll
    for (int j = 0; j < 8; ++j)
#pragma unroll
      for (int g = 0; g < 3; ++g)
        xs[j][g] = cok[g] ? out[(unsigned)(f + j) * ROW + col[g]] : 0.0f;
#pragma unroll
    for (int j = 0; j < 8; ++j)
#pragma unroll
      for (int g = 0; g < 3; ++g) acc2[g] = fmaf(xs[j][g], xs[j][g], acc2[g]);
  }
  for (; f < end; ++f) {
#pragma unroll
    for (int g = 0; g < 3; ++g) {
      float vv = cok[g] ? out[(unsigned)f * ROW + col[g]] : 0.0f;
      acc2[g] = fmaf(vv, vv, acc2[g]);
    }
  }
#pragma unroll
  for (int g = 0; g < 3; ++g)
    if (cok[g]) part[(unsigned)c * ROW + col[g]] = acc2[g];
  if (t < NBINS) part[(unsigned)c * ROW + NBINS + t] = acc1;
}

// ---------- finalize norms: one block per column, LDS tree (deterministic) ----------
__global__ __launch_bounds__(256) void k_norm(const float* __restrict__ part,
                                              float* __restrict__ invn, int nblk) {
  __shared__ float red[256];
  int c = blockIdx.x, t = threadIdx.x;
  float s = 0.0f;
  for (int b = t; b < nblk; b += 256) s += part[(unsigned)b * ROW + c];
  red[t] = s;
  __syncthreads();
  for (int o = 128; o > 0; o >>= 1) {
    if (t < o) red[t] += red[t + o];
    __syncthreads();
  }
  if (t == 0) invn[c] = 1.0f / fmaxf(sqrtf(red[0]), 1e-12f);
}

// ---------- scale pass ----------
__global__ __launch_bounds__(256) void k_scale(float4* __restrict__ out4,
                                               const float* __restrict__ invn,
                                               long n4) {
  __shared__ float inv[ROW];
  for (int i = threadIdx.x; i < ROW; i += 256) inv[i] = invn[i];
  __syncthreads();
  long stride = (long)gridDim.x * 256;
  for (long i = (long)blockIdx.x * 256 + threadIdx.x; i < n4; i += stride) {
    float4 v = out4[i];
    int col = (int)((i * 4) % ROW);
    v.x *= inv[col];
    v.y *= inv[col + 1];
    v.z *= inv[col + 2];
    v.w *= inv[col + 3];
    out4[i] = v;
  }
}

extern "C" void kernel_launch(void* const* d_in, const int* in_sizes, int n_in,
                              void* d_out, int out_size, void* d_ws, size_t ws_size,
                              hipStream_t stream) {
  const float* audio = (const float*)d_in[0];
  const float* fb = (const float*)d_in[1];
  int T = in_sizes[0];
  int nframes = 1 + T / HOP;  // center=True, pad = NFFT/2 both sides
  float* out = (float*)d_out;
  int chunks = (nframes + CHUNK - 1) / CHUNK;

  // ws layout (floats): twg[1024] | mend[chunks*257] | vinit[chunks*257] |
  //                     invn[1028] | lohi[514](int) | pad | part[chunks*1028]
  float* wsf = (float*)d_ws;
  float2* twg = (float2*)wsf;
  float* mend = wsf + 1024;
  float* vinit = mend + (long)chunks * NBINS;
  float* invn = vinit + (long)chunks * NBINS;
  int* lohi = (int*)(invn + ROW);
  long base = 1024 + 2L * chunks * NBINS + ROW + 2 * NBINS;
  base = (base + 3) & ~3L;
  float* part = wsf + base;

  k_prep<<<1, 256, 0, stream>>>(fb, lohi, twg);
  k_fft<<<(nframes + 3) / 4, 256, 0, stream>>>(audio, fb, lohi, twg, out, T, nframes);
  k_pcen_a<<<chunks, 320, 0, stream>>>(out, mend, nframes);
  k_pcen_b<<<1, 320, 0, stream>>>(mend, vinit, chunks);
  k_pcen_c<<<chunks, 320, 0, stream>>>(out, vinit, part, nframes);
  k_norm<<<ROW, 256, 0, stream>>>(part, invn, chunks);
  long n4 = (long)nframes * ROW / 4;
  k_scale<<<2048, 256, 0, stream>>>((float4*)out, invn, n4);
}

// Round 11
// 228.775 us; speedup vs baseline: 1.3811x; 1.0041x over previous
//
#include <hip/hip_runtime.h>
#include <math.h>

#define NFFT 512
#define HOP 128
#define NBINS 257
#define ROW 1028          // 4*257
#define CHUNK 64
#define LAM64 0.19783147f // 0.975^64
// LDS swizzle for FFT buffers: bijective, applied to EVERY access.
#define SWZ(a) ((a) ^ (((a) >> 4) & 15))

__device__ __forceinline__ float2 cmul(float2 a, float2 b) {
  return make_float2(a.x * b.x - a.y * b.y, a.x * b.y + a.y * b.x);
}

struct EB { float lg, sv, cv; };

// ---------- prep: twiddle table (once) + sparse filterbank spans ----------
__global__ void k_prep(const float* __restrict__ fb, int* __restrict__ lohi,
                       float2* __restrict__ twg) {
  int t = threadIdx.x;
  for (int i = t; i < NFFT; i += 256) {
    double ang = -6.283185307179586476925286766559 * (double)i / (double)NFFT;
    twg[i] = make_float2((float)cos(ang), (float)sin(ang));
  }
  for (int m = t; m < NBINS; m += 256) {
    int lo = 0, hi = -1;
    for (int f = 0; f < NBINS; ++f) {
      if (fb[f * NBINS + m] != 0.0f) { if (hi < 0) lo = f; hi = f; }
    }
    lohi[m] = lo;
    lohi[NBINS + m] = hi;
  }
}

// ---------- per-bin epilogue (S = swizzled LDS array, off = subarray base) ----------
__device__ __forceinline__ EB epilogue_bin(const float2* __restrict__ S, int off,
                                           float* __restrict__ mspec,
                                           float* __restrict__ out, unsigned ob,
                                           int k, bool store) {
  float2 z = S[SWZ(off + k)];
  float mag, sv, cv;
  if (k == 0 || k == 256) {
    // z.y is EXACTLY 0 here (unpack cancels identically at k==m). The f32
    // reference computes sin(atan2(+0, re)) = sin(pi_f32) = -8.742278e-8 when
    // re<0 — NOT 0. F.normalize scales that column to -1/sqrt(N_neg), so we
    // must emit the same tiny values for the norm to match.
    mag = fabsf(z.x);
    sv = sinf(atan2f(0.0f, z.x));
    cv = copysignf(1.0f, z.x);
  } else {
    float r2 = fmaf(z.x, z.x, z.y * z.y);
    if (r2 > 0.0f) {
      float rs = __builtin_amdgcn_rsqf(r2);
      mag = r2 * rs;            // sqrt(r2) to ~1ulp
      sv = z.y * rs;            // sin(angle) = im/|z|
      cv = z.x * rs;            // cos(angle) = re/|z|
    } else { mag = 0.0f; sv = 0.0f; cv = 1.0f; }
  }
  float lg = __logf(mag + 1e-9f);
  if (store) {
    out[ob + k] = lg;
    out[ob + 2 * NBINS + k] = sv;
    out[ob + 3 * NBINS + k] = cv;
  }
  // hann spectrum via 3-tap stencil; X[-1] = conj(X[1])
  float2 zm, zp;
  if (k == 0) { float2 s1 = S[SWZ(off + 1)]; zm = make_float2(s1.x, -s1.y); }
  else zm = S[SWZ(off + k - 1)];
  zp = S[SWZ(off + k + 1)];
  float hr = 0.5f * z.x - 0.25f * (zm.x + zp.x);
  float hi = 0.5f * z.y - 0.25f * (zm.y + zp.y);
  mspec[k] = hr * hr + hi * hi;
  EB e; e.lg = lg; e.sv = sv; e.cv = cv;
  return e;
}

// ---------- 4 frames per block: 2 complex FFTs, radix-4 (fused 2x radix-2) ----------
// Also emits per-block column-sumsq partials for ch0/2/3 (values are in
// registers here — saves pcen_c's 115MB re-read). Layout per partF row:
// i in [0,771): col = i<257 ? i : 257+i (ch0, ch2, ch3 absolute columns).
__global__ __launch_bounds__(256) void k_fft(
    const float* __restrict__ audio, const float* __restrict__ fb,
    const int* __restrict__ lohi, const float2* __restrict__ twg,
    float* __restrict__ out, float* __restrict__ partF, int T, int nframes) {
  __shared__ float2 bufA[2][520];
  __shared__ float2 bufB[2][520];
  __shared__ float2 twL[NFFT];
  __shared__ float mspec[4][NBINS];

  const int t = threadIdx.x;
  const int ff = t >> 7;       // which FFT (0/1)
  const int v = t & 127;       // butterfly index within FFT
  const int frb = blockIdx.x * 4;
  const int fr0 = frb + 2 * ff;
  const int fr1 = fr0 + 1;
  const bool h0 = fr0 < nframes;
  const bool h1 = fr1 < nframes;

  for (int i = t; i < NFFT; i += 256) twL[i] = twg[i];

  float2* __restrict__ xa = bufA[ff];
  float2* __restrict__ xb = bufB[ff];

  // load packed frame pair with reflect padding: z = frame0 + i*frame1
  int s0 = fr0 * HOP - NFFT / 2;
  for (int i = v; i < NFFT; i += 128) {
    int q0 = s0 + i;
    if (q0 < 0) q0 = -q0;
    if (q0 >= T) q0 = 2 * T - 2 - q0;
    int q1 = s0 + HOP + i;
    if (q1 < 0) q1 = -q1;
    if (q1 >= T) q1 = 2 * T - 2 - q1;
    xa[SWZ(i)] = make_float2(audio[q0], h1 ? audio[q1] : 0.0f);
  }
  __syncthreads();

  float2 *x = xa, *y = xb;
#pragma unroll
  for (int ds = 0; ds < 4; ++ds) {
    const int m = 1 << (2 * ds);
    int qm = v & ~(m - 1);
    int r = v - qm;
    int o = 4 * qm + r;
    float2 x0 = x[SWZ(v)], x1 = x[SWZ(v + 128)], x2 = x[SWZ(v + 256)], x3 = x[SWZ(v + 384)];
    float2 s02 = make_float2(x0.x + x2.x, x0.y + x2.y);
    float2 d02 = make_float2(x0.x - x2.x, x0.y - x2.y);
    float2 s13 = make_float2(x1.x + x3.x, x1.y + x3.y);
    float2 d13 = make_float2(x1.x - x3.x, x1.y - x3.y);
    float2 E0 = make_float2(s02.x + s13.x, s02.y + s13.y);
    float2 u1 = make_float2(d02.x + d13.y, d02.y - d13.x);  // d02 - i*d13
    float2 u2 = make_float2(s02.x - s13.x, s02.y - s13.y);
    float2 u3 = make_float2(d02.x - d13.y, d02.y + d13.x);  // d02 + i*d13
    float2 E1 = cmul(twL[qm], u1);
    float2 E2 = cmul(twL[2 * qm], u2);
    float2 E3 = cmul(twL[3 * qm], u3);
    y[SWZ(o)] = E0;
    y[SWZ(o + m)] = E1;
    y[SWZ(o + 2 * m)] = E2;
    y[SWZ(o + 3 * m)] = E3;
    __syncthreads();
    float2* tmp = x; x = y; y = tmp;
  }
  // Final radix-2 is twiddle-free; fuse into the unpack (reconstruct Zk, Z512-k
  // directly from stage-3 output in x), skipping one LDS round-trip + barrier.
  for (int k = v; k < 258; k += 128) {
    float2 Zk, Zm;
    if (k <= 255) {
      float2 a0 = x[SWZ(k)], a1 = x[SWZ(k + 256)];
      Zk = make_float2(a0.x + a1.x, a0.y + a1.y);
    } else {
      float2 a0 = x[SWZ(k - 256)], a1 = x[SWZ(k)];
      Zk = make_float2(a0.x - a1.x, a0.y - a1.y);
    }
    int m2 = (NFFT - k) & (NFFT - 1);
    if (k == 0 || k == 256) {
      Zm = Zk;                       // structural: X1.im = X2.im = 0 exactly
    } else if (m2 >= 256) {          // k in 1..255
      float2 b0 = x[SWZ(m2 - 256)], b1 = x[SWZ(m2)];
      Zm = make_float2(b0.x - b1.x, b0.y - b1.y);
    } else {                         // k == 257 -> m2 = 255
      float2 b0 = x[SWZ(m2)], b1 = x[SWZ(m2 + 256)];
      Zm = make_float2(b0.x + b1.x, b0.y + b1.y);
    }
    y[SWZ(k)] = make_float2(0.5f * (Zk.x + Zm.x), 0.5f * (Zk.y - Zm.y));
    y[SWZ(258 + k)] = make_float2(0.5f * (Zk.y + Zm.y), 0.5f * (Zm.x - Zk.x));
  }
  __syncthreads();
  // x (bufA[ff]) is now free: reuse as float scratch for per-bin squares.
  // Region layout: ch0 at [0..257), ch2 at [258..515), ch3 at [516..773).
  float* sqf = (float*)&bufA[ff][0];

  unsigned ob0 = (unsigned)fr0 * ROW;
  unsigned ob1 = (unsigned)fr1 * ROW;
  for (int k = v; k < NBINS; k += 128) {
    EB e0 = epilogue_bin(y, 0, mspec[2 * ff], out, ob0, k, h0);
    EB e1 = epilogue_bin(y, 258, mspec[2 * ff + 1], out, ob1, k, h1);
    sqf[k]       = (h0 ? e0.lg * e0.lg : 0.f) + (h1 ? e1.lg * e1.lg : 0.f);
    sqf[258 + k] = (h0 ? e0.sv * e0.sv : 0.f) + (h1 ? e1.sv * e1.sv : 0.f);
    sqf[516 + k] = (h0 ? e0.cv * e0.cv : 0.f) + (h1 ? e1.cv * e1.cv : 0.f);
  }
  __syncthreads();

  // sparse mel for both frames of this FFT
  for (int m = v; m < NBINS; m += 128) {
    int lo = lohi[m], hi = lohi[NBINS + m];
    float a0 = 0.0f, a1 = 0.0f;
    for (int f = lo; f <= hi; ++f) {
      float w = fb[f * NBINS + m];
      a0 = fmaf(mspec[2 * ff][f], w, a0);
      a1 = fmaf(mspec[2 * ff + 1][f], w, a1);
    }
    if (h0) out[ob0 + NBINS + m] = a0;
    if (h1) out[ob1 + NBINS + m] = a1;
  }

  // combine both FFTs' squares -> compact 771-float partial row per block
  const float* sq0 = (const float*)&bufA[0][0];
  const float* sq1 = (const float*)&bufA[1][0];
  for (int i = t; i < 771; i += 256) {
    int lidx = i + (i >= 257) + (i >= 514);
    partF[(unsigned)blockIdx.x * 771u + i] = sq0[lidx] + sq1[lidx];
  }
}

// ---------- pcen phase A: local chunk scan from zero -> mend ----------
__global__ __launch_bounds__(320) void k_pcen_a(const float* __restrict__ out,
                                                float* __restrict__ mend, int nframes) {
  int m = threadIdx.x;
  if (m >= NBINS) return;
  int c = blockIdx.x;
  int F0 = c * CHUNK;
  int end = min(F0 + CHUNK, nframes);
  const float SS = 0.025f, OMS = 1.0f - SS;
  float mm = 0.0f;
  int tf = F0;
  for (; tf + 16 <= end; tf += 16) {
    float xs[16];
#pragma unroll
    for (int j = 0; j < 16; ++j) xs[j] = out[(unsigned)(tf + j) * ROW + NBINS + m];
#pragma unroll
    for (int j = 0; j < 16; ++j) mm = OMS * mm + SS * xs[j];
  }
  for (; tf < end; ++tf) mm = OMS * mm + SS * out[(unsigned)tf * ROW + NBINS + m];
  mend[c * NBINS + m] = mm;
}

// ---------- pcen phase C: init from prev 12 chunks' mend (LAM64^12=3.6e-9),
// scan+rewrite ch1; ch1 column-square partials free from registers ----------
__global__ __launch_bounds__(320) void k_pcen_c(float* __restrict__ out,
                                                const float* __restrict__ mend,
                                                float* __restrict__ partC,
                                                int nframes) {
  int m = threadIdx.x;
  if (m >= NBINS) return;
  int c = blockIdx.x;
  int F0 = c * CHUNK;
  int end = min(F0 + CHUNK, nframes);
  const float SS = 0.025f, OMS = 1.0f - SS;
  const float SQ2 = sqrtf(2.0f);
  float mm;
  if (c >= 12) {
    float xs[12];
#pragma unroll
    for (int j = 0; j < 12; ++j) xs[j] = mend[(c - 12 + j) * NBINS + m];
    mm = 0.0f;
#pragma unroll
    for (int j = 0; j < 12; ++j) mm = xs[j] + LAM64 * mm;
  } else {
    mm = 0.0f;
    for (int j = 0; j < c; ++j) mm = mend[j * NBINS + m] + LAM64 * mm;
  }
  float acc1 = 0.0f;
  int tf = F0;
  for (; tf + 16 <= end; tf += 16) {
    float xs[16], ys[16];
#pragma unroll
    for (int j = 0; j < 16; ++j) xs[j] = out[(unsigned)(tf + j) * ROW + NBINS + m];
#pragma unroll
    for (int j = 0; j < 16; ++j) {
      mm = OMS * mm + SS * xs[j];
      float invden = __expf(-0.98f * __logf(mm + 1e-6f));  // 1/den, no division
      float val = fmaf(xs[j], invden, 2.0f);
      float rs = __builtin_amdgcn_rsqf(val);
      ys[j] = val * rs - SQ2;   // sqrt(val) - sqrt(2), ~1ulp
      acc1 = fmaf(ys[j], ys[j], acc1);
    }
#pragma unroll
    for (int j = 0; j < 16; ++j) out[(unsigned)(tf + j) * ROW + NBINS + m] = ys[j];
  }
  for (; tf < end; ++tf) {
    unsigned idx = (unsigned)tf * ROW + NBINS + m;
    float xv = out[idx];
    mm = OMS * mm + SS * xv;
    float invden = __expf(-0.98f * __logf(mm + 1e-6f));
    float val = fmaf(xv, invden, 2.0f);
    float rs = __builtin_amdgcn_rsqf(val);
    float yv = val * rs - SQ2;
    acc1 = fmaf(yv, yv, acc1);
    out[idx] = yv;
  }
  partC[c * NBINS + m] = acc1;
}

// ---------- finalize norms: one block per column (deterministic tree) ----------
// ch1 cols (257..513): sum partC (chunks x 257). Others: partF (nfb x 771).
__global__ __launch_bounds__(256) void k_norm(const float* __restrict__ partF,
                                              const float* __restrict__ partC,
                                              float* __restrict__ invn,
                                              int nfb, int chunks) {
  __shared__ float red[256];
  int c = blockIdx.x, t = threadIdx.x;
  float s = 0.0f;
  if (c >= 257 && c < 514) {
    int m = c - 257;
    for (int r = t; r < chunks; r += 256) s += partC[r * NBINS + m];
  } else {
    int i = (c < 257) ? c : c - 257;
    for (int r = t; r < nfb; r += 256) s += partF[(unsigned)r * 771u + i];
  }
  red[t] = s;
  __syncthreads();
  for (int o = 128; o > 0; o >>= 1) {
    if (t < o) red[t] += red[t + o];
    __syncthreads();
  }
  if (t == 0) invn[c] = 1.0f / fmaxf(sqrtf(red[0]), 1e-12f);
}

// ---------- scale pass ----------
__global__ __launch_bounds__(256) void k_scale(float4* __restrict__ out4,
                                               const float* __restrict__ invn,
                                               long n4) {
  __shared__ float inv[ROW];
  for (int i = threadIdx.x; i < ROW; i += 256) inv[i] = invn[i];
  __syncthreads();
  long stride = (long)gridDim.x * 256;
  for (long i = (long)blockIdx.x * 256 + threadIdx.x; i < n4; i += stride) {
    float4 v = out4[i];
    int col = (int)((i * 4) % ROW);
    v.x *= inv[col];
    v.y *= inv[col + 1];
    v.z *= inv[col + 2];
    v.w *= inv[col + 3];
    out4[i] = v;
  }
}

extern "C" void kernel_launch(void* const* d_in, const int* in_sizes, int n_in,
                              void* d_out, int out_size, void* d_ws, size_t ws_size,
                              hipStream_t stream) {
  const float* audio = (const float*)d_in[0];
  const float* fb = (const float*)d_in[1];
  int T = in_sizes[0];
  int nframes = 1 + T / HOP;  // center=True, pad = NFFT/2 both sides
  float* out = (float*)d_out;
  int chunks = (nframes + CHUNK - 1) / CHUNK;
  int nfb = (nframes + 3) / 4;

  // ws layout (floats): twg[1024] | mend[chunks*257] | invn[1028] |
  //                     lohi[514](int) | partC[chunks*257] | partF[nfb*771]
  float* wsf = (float*)d_ws;
  float2* twg = (float2*)wsf;
  float* mend = wsf + 1024;
  float* invn = mend + (long)chunks * NBINS;
  int* lohi = (int*)(invn + ROW);
  float* partC = (float*)(lohi + 2 * NBINS);
  float* partF = partC + (long)chunks * NBINS;

  k_prep<<<1, 256, 0, stream>>>(fb, lohi, twg);
  k_fft<<<nfb, 256, 0, stream>>>(audio, fb, lohi, twg, out, partF, T, nframes);
  k_pcen_a<<<chunks, 320, 0, stream>>>(out, mend, nframes);
  k_pcen_c<<<chunks, 320, 0, stream>>>(out, mend, partC, nframes);
  k_norm<<<ROW, 256, 0, stream>>>(partF, partC, invn, nfb, chunks);
  long n4 = (long)nframes * ROW / 4;
  k_scale<<<2048, 256, 0, stream>>>((float4*)out, invn, n4);
}

// Round 13
// 218.432 us; speedup vs baseline: 1.4465x; 1.0473x over previous
//
#include <hip/hip_runtime.h>
#include <math.h>

#define NFFT 512
#define HOP 128
#define NBINS 257
#define ROW 1028          // 4*257
#define CHUNK 64
#define LAM64 0.19783147f // 0.975^64
// LDS swizzle for FFT buffers: bijective, applied to EVERY access.
#define SWZ(a) ((a) ^ (((a) >> 4) & 15))

__device__ __forceinline__ float2 cmul(float2 a, float2 b) {
  return make_float2(a.x * b.x - a.y * b.y, a.x * b.y + a.y * b.x);
}

struct EB { float lg, sv, cv, msp; };

// ---------- prep: twiddle table (once) + sparse filterbank spans ----------
__global__ void k_prep(const float* __restrict__ fb, int* __restrict__ lohi,
                       float2* __restrict__ twg) {
  int t = threadIdx.x;
  for (int i = t; i < NFFT; i += 256) {
    double ang = -6.283185307179586476925286766559 * (double)i / (double)NFFT;
    twg[i] = make_float2((float)cos(ang), (float)sin(ang));
  }
  for (int m = t; m < NBINS; m += 256) {
    int lo = 0, hi = -1;
    for (int f = 0; f < NBINS; ++f) {
      if (fb[f * NBINS + m] != 0.0f) { if (hi < 0) lo = f; hi = f; }
    }
    lohi[m] = lo;
    lohi[NBINS + m] = hi;
  }
}

// ---------- per-bin epilogue (S = swizzled LDS array, off = subarray base) ----------
__device__ __forceinline__ EB epilogue_bin(const float2* __restrict__ S, int off,
                                           float* __restrict__ out, unsigned ob,
                                           int k, bool store) {
  float2 z = S[SWZ(off + k)];
  float mag, sv, cv;
  if (k == 0 || k == 256) {
    // z.y is EXACTLY 0 here (unpack cancels identically at k==m). The f32
    // reference computes sin(atan2(+0, re)) = sin(pi_f32) = -8.742278e-8 when
    // re<0 — NOT 0. F.normalize scales that column to -1/sqrt(N_neg), so we
    // must emit the same tiny values for the norm to match.
    mag = fabsf(z.x);
    sv = sinf(atan2f(0.0f, z.x));
    cv = copysignf(1.0f, z.x);
  } else {
    float r2 = fmaf(z.x, z.x, z.y * z.y);
    if (r2 > 0.0f) {
      float rs = __builtin_amdgcn_rsqf(r2);
      mag = r2 * rs;            // sqrt(r2) to ~1ulp
      sv = z.y * rs;            // sin(angle) = im/|z|
      cv = z.x * rs;            // cos(angle) = re/|z|
    } else { mag = 0.0f; sv = 0.0f; cv = 1.0f; }
  }
  float lg = __logf(mag + 1e-9f);
  if (store) {
    out[ob + k] = lg;
    out[ob + 2 * NBINS + k] = sv;
    out[ob + 3 * NBINS + k] = cv;
  }
  // hann spectrum via 3-tap stencil; X[-1] = conj(X[1])
  float2 zm, zp;
  if (k == 0) { float2 s1 = S[SWZ(off + 1)]; zm = make_float2(s1.x, -s1.y); }
  else zm = S[SWZ(off + k - 1)];
  zp = S[SWZ(off + k + 1)];
  float hr = 0.5f * z.x - 0.25f * (zm.x + zp.x);
  float hi = 0.5f * z.y - 0.25f * (zm.y + zp.y);
  EB e; e.lg = lg; e.sv = sv; e.cv = cv; e.msp = hr * hr + hi * hi;
  return e;
}

// ---------- 4 frames per block: 2 complex FFTs, radix-4 (fused 2x radix-2) ----------
// LDS = bufA+bufB only (16.6KB): twiddles read straight from global (L2-hot,
// 4KB shared by all blocks); mspec parked in bufB after the epilogue barrier.
// Emits per-block column-sumsq partials for ch0/2/3 (partF rows of 771).
__global__ __launch_bounds__(256) void k_fft(
    const float* __restrict__ audio, const float* __restrict__ fb,
    const int* __restrict__ lohi, const float2* __restrict__ twg,
    float* __restrict__ out, float* __restrict__ partF, int T, int nframes) {
  __shared__ float2 bufA[2][520];
  __shared__ float2 bufB[2][520];

  const int t = threadIdx.x;
  const int ff = t >> 7;       // which FFT (0/1)
  const int v = t & 127;       // butterfly index within FFT
  const int frb = blockIdx.x * 4;
  const int fr0 = frb + 2 * ff;
  const int fr1 = fr0 + 1;
  const bool h0 = fr0 < nframes;
  const bool h1 = fr1 < nframes;

  float2* __restrict__ xa = bufA[ff];
  float2* __restrict__ xb = bufB[ff];

  // load packed frame pair with reflect padding: z = frame0 + i*frame1
  int s0 = fr0 * HOP - NFFT / 2;
  for (int i = v; i < NFFT; i += 128) {
    int q0 = s0 + i;
    if (q0 < 0) q0 = -q0;
    if (q0 >= T) q0 = 2 * T - 2 - q0;
    int q1 = s0 + HOP + i;
    if (q1 < 0) q1 = -q1;
    if (q1 >= T) q1 = 2 * T - 2 - q1;
    xa[SWZ(i)] = make_float2(audio[q0], h1 ? audio[q1] : 0.0f);
  }
  __syncthreads();

  float2 *x = xa, *y = xb;
  for (int ds = 0; ds < 4; ++ds) {
    const int m = 1 << (2 * ds);
    int qm = v & ~(m - 1);
    int r = v - qm;
    int o = 4 * qm + r;
    // twiddles straight from global (no LDS staging)
    float2 w1 = twg[qm];
    float2 w2 = twg[2 * qm];
    float2 w3 = twg[3 * qm];
    float2 x0 = x[SWZ(v)], x1 = x[SWZ(v + 128)], x2 = x[SWZ(v + 256)], x3 = x[SWZ(v + 384)];
    float2 s02 = make_float2(x0.x + x2.x, x0.y + x2.y);
    float2 d02 = make_float2(x0.x - x2.x, x0.y - x2.y);
    float2 s13 = make_float2(x1.x + x3.x, x1.y + x3.y);
    float2 d13 = make_float2(x1.x - x3.x, x1.y - x3.y);
    float2 E0 = make_float2(s02.x + s13.x, s02.y + s13.y);
    float2 u1 = make_float2(d02.x + d13.y, d02.y - d13.x);  // d02 - i*d13
    float2 u2 = make_float2(s02.x - s13.x, s02.y - s13.y);
    float2 u3 = make_float2(d02.x - d13.y, d02.y + d13.x);  // d02 + i*d13
    float2 E1 = cmul(w1, u1);
    float2 E2 = cmul(w2, u2);
    float2 E3 = cmul(w3, u3);
    y[SWZ(o)] = E0;
    y[SWZ(o + m)] = E1;
    y[SWZ(o + 2 * m)] = E2;
    y[SWZ(o + 3 * m)] = E3;
    __syncthreads();
    float2* tmp = x; x = y; y = tmp;
  }
  // After 4 swaps: x == bufA (stage-3 output), y == bufB.
  // Final radix-2 is twiddle-free; fuse into the unpack (reconstruct Zk, Z512-k
  // directly from stage-3 output in x), skipping one LDS round-trip + barrier.
  for (int k = v; k < 258; k += 128) {
    float2 Zk, Zm;
    if (k <= 255) {
      float2 a0 = x[SWZ(k)], a1 = x[SWZ(k + 256)];
      Zk = make_float2(a0.x + a1.x, a0.y + a1.y);
    } else {
      float2 a0 = x[SWZ(k - 256)], a1 = x[SWZ(k)];
      Zk = make_float2(a0.x - a1.x, a0.y - a1.y);
    }
    int m2 = (NFFT - k) & (NFFT - 1);
    if (k == 0 || k == 256) {
      Zm = Zk;                       // structural: X1.im = X2.im = 0 exactly
    } else if (m2 >= 256) {          // k in 1..255
      float2 b0 = x[SWZ(m2 - 256)], b1 = x[SWZ(m2)];
      Zm = make_float2(b0.x - b1.x, b0.y - b1.y);
    } else {                         // k == 257 -> m2 = 255
      float2 b0 = x[SWZ(m2)], b1 = x[SWZ(m2 + 256)];
      Zm = make_float2(b0.x + b1.x, b0.y + b1.y);
    }
    y[SWZ(k)] = make_float2(0.5f * (Zk.x + Zm.x), 0.5f * (Zk.y - Zm.y));
    y[SWZ(258 + k)] = make_float2(0.5f * (Zk.y + Zm.y), 0.5f * (Zm.x - Zk.x));
  }
  __syncthreads();

  // epilogue: compute per-bin outputs, hold mspec/squares in registers
  // (static [3] arrays, fully unrolled -> stays in VGPRs)
  unsigned ob0 = (unsigned)fr0 * ROW;
  unsigned ob1 = (unsigned)fr1 * ROW;
  float mspA[3], mspB[3], sql[3], sqs[3], sqc[3];
#pragma unroll
  for (int ki = 0; ki < 3; ++ki) {
    int k = v + 128 * ki;
    if (k <= 256) {
      EB e0 = epilogue_bin(y, 0, out, ob0, k, h0);
      EB e1 = epilogue_bin(y, 258, out, ob1, k, h1);
      mspA[ki] = e0.msp;
      mspB[ki] = e1.msp;
      sql[ki] = (h0 ? e0.lg * e0.lg : 0.f) + (h1 ? e1.lg * e1.lg : 0.f);
      sqs[ki] = (h0 ? e0.sv * e0.sv : 0.f) + (h1 ? e1.sv * e1.sv : 0.f);
      sqc[ki] = (h0 ? e0.cv * e0.cv : 0.f) + (h1 ? e1.cv * e1.cv : 0.f);
    }
  }
  __syncthreads();   // all reads of y (spectra) done -> bufB reusable

  // park: mspec (both frames) in bufB[ff]; squares (sqf) in bufA[ff]
  float* mspSh = (float*)&bufB[ff][0];  // [0..257) frame0, [258..515) frame1
  float* sqf = (float*)&bufA[ff][0];    // ch0 at [0..257), ch2 at [258..515), ch3 at [516..773)
#pragma unroll
  for (int ki = 0; ki < 3; ++ki) {
    int k = v + 128 * ki;
    if (k <= 256) {
      mspSh[k] = mspA[ki];
      mspSh[258 + k] = mspB[ki];
      sqf[k] = sql[ki];
      sqf[258 + k] = sqs[ki];
      sqf[516 + k] = sqc[ki];
    }
  }
  __syncthreads();

  // sparse mel for both frames of this FFT
  for (int m = v; m < NBINS; m += 128) {
    int lo = lohi[m], hi = lohi[NBINS + m];
    float a0 = 0.0f, a1 = 0.0f;
    for (int f = lo; f <= hi; ++f) {
      float w = fb[f * NBINS + m];
      a0 = fmaf(mspSh[f], w, a0);
      a1 = fmaf(mspSh[258 + f], w, a1);
    }
    if (h0) out[ob0 + NBINS + m] = a0;
    if (h1) out[ob1 + NBINS + m] = a1;
  }

  // combine both FFTs' squares -> compact 771-float partial row per block.
  // sqf has GAPS at 257 and 515 (regions are 258-strided): lidx skips them.
  // (Round-12 bug: reading sq[i] directly picked up uninitialized holes and
  // shifted ch2/ch3 by one -> garbage norms.)
  const float* sq0 = (const float*)&bufA[0][0];
  const float* sq1 = (const float*)&bufA[1][0];
  for (int i = t; i < 771; i += 256) {
    int lidx = i + (i >= 257) + (i >= 514);
    partF[(unsigned)blockIdx.x * 771u + i] = sq0[lidx] + sq1[lidx];
  }
}

// ---------- pcen phase A: local chunk scan from zero -> mend ----------
__global__ __launch_bounds__(320) void k_pcen_a(const float* __restrict__ out,
                                                float* __restrict__ mend, int nframes) {
  int m = threadIdx.x;
  if (m >= NBINS) return;
  int c = blockIdx.x;
  int F0 = c * CHUNK;
  int end = min(F0 + CHUNK, nframes);
  const float SS = 0.025f, OMS = 1.0f - SS;
  float mm = 0.0f;
  int tf = F0;
  for (; tf + 16 <= end; tf += 16) {
    float xs[16];
#pragma unroll
    for (int j = 0; j < 16; ++j) xs[j] = out[(unsigned)(tf + j) * ROW + NBINS + m];
#pragma unroll
    for (int j = 0; j < 16; ++j) mm = OMS * mm + SS * xs[j];
  }
  for (; tf < end; ++tf) mm = OMS * mm + SS * out[(unsigned)tf * ROW + NBINS + m];
  mend[c * NBINS + m] = mm;
}

// ---------- pcen phase C: init from prev 12 chunks' mend (LAM64^12=3.6e-9),
// scan+rewrite ch1; ch1 column-square partials free from registers ----------
__global__ __launch_bounds__(320) void k_pcen_c(float* __restrict__ out,
                                                const float* __restrict__ mend,
                                                float* __restrict__ partC,
                                                int nframes) {
  int m = threadIdx.x;
  if (m >= NBINS) return;
  int c = blockIdx.x;
  int F0 = c * CHUNK;
  int end = min(F0 + CHUNK, nframes);
  const float SS = 0.025f, OMS = 1.0f - SS;
  const float SQ2 = sqrtf(2.0f);
  float mm;
  if (c >= 12) {
    float xs[12];
#pragma unroll
    for (int j = 0; j < 12; ++j) xs[j] = mend[(c - 12 + j) * NBINS + m];
    mm = 0.0f;
#pragma unroll
    for (int j = 0; j < 12; ++j) mm = xs[j] + LAM64 * mm;
  } else {
    mm = 0.0f;
    for (int j = 0; j < c; ++j) mm = mend[j * NBINS + m] + LAM64 * mm;
  }
  float acc1 = 0.0f;
  int tf = F0;
  for (; tf + 16 <= end; tf += 16) {
    float xs[16], ys[16];
#pragma unroll
    for (int j = 0; j < 16; ++j) xs[j] = out[(unsigned)(tf + j) * ROW + NBINS + m];
#pragma unroll
    for (int j = 0; j < 16; ++j) {
      mm = OMS * mm + SS * xs[j];
      float invden = __expf(-0.98f * __logf(mm + 1e-6f));  // 1/den, no division
      float val = fmaf(xs[j], invden, 2.0f);
      float rs = __builtin_amdgcn_rsqf(val);
      ys[j] = val * rs - SQ2;   // sqrt(val) - sqrt(2), ~1ulp
      acc1 = fmaf(ys[j], ys[j], acc1);
    }
#pragma unroll
    for (int j = 0; j < 16; ++j) out[(unsigned)(tf + j) * ROW + NBINS + m] = ys[j];
  }
  for (; tf < end; ++tf) {
    unsigned idx = (unsigned)tf * ROW + NBINS + m;
    float xv = out[idx];
    mm = OMS * mm + SS * xv;
    float invden = __expf(-0.98f * __logf(mm + 1e-6f));
    float val = fmaf(xv, invden, 2.0f);
    float rs = __builtin_amdgcn_rsqf(val);
    float yv = val * rs - SQ2;
    acc1 = fmaf(yv, yv, acc1);
    out[idx] = yv;
  }
  partC[c * NBINS + m] = acc1;
}

// ---------- finalize norms: one block per column (deterministic tree) ----------
__global__ __launch_bounds__(256) void k_norm(const float* __restrict__ partF,
                                              const float* __restrict__ partC,
                                              float* __restrict__ invn,
                                              int nfb, int chunks) {
  __shared__ float red[256];
  int c = blockIdx.x, t = threadIdx.x;
  float s = 0.0f;
  if (c >= 257 && c < 514) {
    int m = c - 257;
    for (int r = t; r < chunks; r += 256) s += partC[r * NBINS + m];
  } else {
    int i = (c < 257) ? c : c - 257;
    for (int r = t; r < nfb; r += 256) s += partF[(unsigned)r * 771u + i];
  }
  red[t] = s;
  __syncthreads();
  for (int o = 128; o > 0; o >>= 1) {
    if (t < o) red[t] += red[t + o];
    __syncthreads();
  }
  if (t == 0) invn[c] = 1.0f / fmaxf(sqrtf(red[0]), 1e-12f);
}

// ---------- scale pass ----------
__global__ __launch_bounds__(256) void k_scale(float4* __restrict__ out4,
                                               const float* __restrict__ invn,
                                               long n4) {
  __shared__ float inv[ROW];
  for (int i = threadIdx.x; i < ROW; i += 256) inv[i] = invn[i];
  __syncthreads();
  long stride = (long)gridDim.x * 256;
  for (long i = (long)blockIdx.x * 256 + threadIdx.x; i < n4; i += stride) {
    float4 v = out4[i];
    int col = (int)((i * 4) % ROW);
    v.x *= inv[col];
    v.y *= inv[col + 1];
    v.z *= inv[col + 2];
    v.w *= inv[col + 3];
    out4[i] = v;
  }
}

extern "C" void kernel_launch(void* const* d_in, const int* in_sizes, int n_in,
                              void* d_out, int out_size, void* d_ws, size_t ws_size,
                              hipStream_t stream) {
  const float* audio = (const float*)d_in[0];
  const float* fb = (const float*)d_in[1];
  int T = in_sizes[0];
  int nframes = 1 + T / HOP;  // center=True, pad = NFFT/2 both sides
  float* out = (float*)d_out;
  int chunks = (nframes + CHUNK - 1) / CHUNK;
  int nfb = (nframes + 3) / 4;

  // ws layout (floats): twg[1024] | mend[chunks*257] | invn[1028] |
  //                     lohi[514](int) | partC[chunks*257] | partF[nfb*771]
  float* wsf = (float*)d_ws;
  float2* twg = (float2*)wsf;
  float* mend = wsf + 1024;
  float* invn = mend + (long)chunks * NBINS;
  int* lohi = (int*)(invn + ROW);
  float* partC = (float*)(lohi + 2 * NBINS);
  float* partF = partC + (long)chunks * NBINS;

  k_prep<<<1, 256, 0, stream>>>(fb, lohi, twg);
  k_fft<<<nfb, 256, 0, stream>>>(audio, fb, lohi, twg, out, partF, T, nframes);
  k_pcen_a<<<chunks, 320, 0, stream>>>(out, mend, nframes);
  k_pcen_c<<<chunks, 320, 0, stream>>>(out, mend, partC, nframes);
  k_norm<<<ROW, 256, 0, stream>>>(partF, partC, invn, nfb, chunks);
  long n4 = (long)nframes * ROW / 4;
  k_scale<<<2048, 256, 0, stream>>>((float4*)out, invn, n4);
}

// Round 14
// 214.451 us; speedup vs baseline: 1.4734x; 1.0186x over previous
//
#include <hip/hip_runtime.h>
#include <math.h>

#define NFFT 512
#define HOP 128
#define NBINS 257
#define ROW 1028          // 4*257
#define CHUNK 64
#define LAM64 0.19783147f // 0.975^64
// LDS swizzle for FFT buffers: bijective, applied to EVERY access.
#define SWZ(a) ((a) ^ (((a) >> 4) & 15))

__device__ __forceinline__ float2 cmul(float2 a, float2 b) {
  return make_float2(a.x * b.x - a.y * b.y, a.x * b.y + a.y * b.x);
}

struct EB { float lg, sv, cv, msp; };

// ---------- prep: twiddle table (once) + sparse filterbank spans ----------
__global__ void k_prep(const float* __restrict__ fb, int* __restrict__ lohi,
                       float2* __restrict__ twg) {
  int t = threadIdx.x;
  for (int i = t; i < NFFT; i += 256) {
    double ang = -6.283185307179586476925286766559 * (double)i / (double)NFFT;
    twg[i] = make_float2((float)cos(ang), (float)sin(ang));
  }
  for (int m = t; m < NBINS; m += 256) {
    int lo = 0, hi = -1;
    for (int f = 0; f < NBINS; ++f) {
      if (fb[f * NBINS + m] != 0.0f) { if (hi < 0) lo = f; hi = f; }
    }
    lohi[m] = lo;
    lohi[NBINS + m] = hi;
  }
}

// ---------- per-bin epilogue (S = swizzled LDS array, off = subarray base) ----------
__device__ __forceinline__ EB epilogue_bin(const float2* __restrict__ S, int off,
                                           float* __restrict__ out, unsigned ob,
                                           int k, bool store) {
  float2 z = S[SWZ(off + k)];
  float mag, sv, cv;
  if (k == 0 || k == 256) {
    // z.y is EXACTLY 0 here (unpack cancels identically at k==m). The f32
    // reference computes sin(atan2(+0, re)) = sin(pi_f32) = -8.742278e-8 when
    // re<0 — NOT 0. F.normalize scales that column to -1/sqrt(N_neg), so we
    // must emit the same tiny values for the norm to match.
    mag = fabsf(z.x);
    sv = sinf(atan2f(0.0f, z.x));
    cv = copysignf(1.0f, z.x);
  } else {
    float r2 = fmaf(z.x, z.x, z.y * z.y);
    if (r2 > 0.0f) {
      float rs = __builtin_amdgcn_rsqf(r2);
      mag = r2 * rs;            // sqrt(r2) to ~1ulp
      sv = z.y * rs;            // sin(angle) = im/|z|
      cv = z.x * rs;            // cos(angle) = re/|z|
    } else { mag = 0.0f; sv = 0.0f; cv = 1.0f; }
  }
  float lg = __logf(mag + 1e-9f);
  if (store) {
    out[ob + k] = lg;
    out[ob + 2 * NBINS + k] = sv;
    out[ob + 3 * NBINS + k] = cv;
  }
  // hann spectrum via 3-tap stencil; X[-1] = conj(X[1])
  float2 zm, zp;
  if (k == 0) { float2 s1 = S[SWZ(off + 1)]; zm = make_float2(s1.x, -s1.y); }
  else zm = S[SWZ(off + k - 1)];
  zp = S[SWZ(off + k + 1)];
  float hr = 0.5f * z.x - 0.25f * (zm.x + zp.x);
  float hi = 0.5f * z.y - 0.25f * (zm.y + zp.y);
  EB e; e.lg = lg; e.sv = sv; e.cv = cv; e.msp = hr * hr + hi * hi;
  return e;
}

// ---------- 4 frames per block: 2 complex FFTs, radix-4 (fused 2x radix-2) ----------
// Stage 0 is fused with the audio load: the stage-0 read pattern
// {v, v+128, v+256, v+384} IS the per-thread load pattern, so the butterfly is
// register-local — the old global->LDS staging pass + barrier + stage-0 LDS
// reads are eliminated (value-identical arithmetic).
// LDS = bufA+bufB only (16.6KB); twiddles from global (4KB, L2-hot);
// mspec parked in bufB after the epilogue barrier.
// Emits per-block column-sumsq partials for ch0/2/3 (partF rows of 771).
__global__ __launch_bounds__(256) void k_fft(
    const float* __restrict__ audio, const float* __restrict__ fb,
    const int* __restrict__ lohi, const float2* __restrict__ twg,
    float* __restrict__ out, float* __restrict__ partF, int T, int nframes) {
  __shared__ float2 bufA[2][520];
  __shared__ float2 bufB[2][520];

  const int t = threadIdx.x;
  const int ff = t >> 7;       // which FFT (0/1)
  const int v = t & 127;       // butterfly index within FFT
  const int frb = blockIdx.x * 4;
  const int fr0 = frb + 2 * ff;
  const int fr1 = fr0 + 1;
  const bool h0 = fr0 < nframes;
  const bool h1 = fr1 < nframes;

  float2* __restrict__ xa = bufA[ff];
  float2* __restrict__ xb = bufB[ff];

  // fused load + stage 0: packed frame pair z = frame0 + i*frame1, reflect pad
  int s0 = fr0 * HOP - NFFT / 2;
  float2 xr[4];
#pragma unroll
  for (int j = 0; j < 4; ++j) {
    int i = v + 128 * j;
    int q0 = s0 + i;
    if (q0 < 0) q0 = -q0;
    if (q0 >= T) q0 = 2 * T - 2 - q0;
    int q1 = s0 + HOP + i;
    if (q1 < 0) q1 = -q1;
    if (q1 >= T) q1 = 2 * T - 2 - q1;
    xr[j] = make_float2(audio[q0], h1 ? audio[q1] : 0.0f);
  }
  {
    // stage 0 (m=1, qm=v, o=4v), register-local
    float2 w1 = twg[v], w2 = twg[2 * v], w3 = twg[3 * v];
    float2 s02 = make_float2(xr[0].x + xr[2].x, xr[0].y + xr[2].y);
    float2 d02 = make_float2(xr[0].x - xr[2].x, xr[0].y - xr[2].y);
    float2 s13 = make_float2(xr[1].x + xr[3].x, xr[1].y + xr[3].y);
    float2 d13 = make_float2(xr[1].x - xr[3].x, xr[1].y - xr[3].y);
    int o = 4 * v;
    xb[SWZ(o)] = make_float2(s02.x + s13.x, s02.y + s13.y);
    xb[SWZ(o + 1)] = cmul(w1, make_float2(d02.x + d13.y, d02.y - d13.x));  // d02 - i*d13
    xb[SWZ(o + 2)] = cmul(w2, make_float2(s02.x - s13.x, s02.y - s13.y));
    xb[SWZ(o + 3)] = cmul(w3, make_float2(d02.x - d13.y, d02.y + d13.x));  // d02 + i*d13
  }
  __syncthreads();

  // stages 1..3: xb -> xa -> xb -> xa (hoisted swizzled read addresses)
  const int ra0 = SWZ(v), ra1 = SWZ(v + 128), ra2 = SWZ(v + 256), ra3 = SWZ(v + 384);
  float2* x = xb;
  float2* y = xa;
#pragma unroll
  for (int ds = 1; ds < 4; ++ds) {
    const int m = 1 << (2 * ds);
    int qm = v & ~(m - 1);
    int r = v - qm;
    int o = 4 * qm + r;
    float2 w1 = twg[qm];
    float2 w2 = twg[2 * qm];
    float2 w3 = twg[3 * qm];
    float2 x0 = x[ra0], x1 = x[ra1], x2 = x[ra2], x3 = x[ra3];
    float2 s02 = make_float2(x0.x + x2.x, x0.y + x2.y);
    float2 d02 = make_float2(x0.x - x2.x, x0.y - x2.y);
    float2 s13 = make_float2(x1.x + x3.x, x1.y + x3.y);
    float2 d13 = make_float2(x1.x - x3.x, x1.y - x3.y);
    float2 E0 = make_float2(s02.x + s13.x, s02.y + s13.y);
    float2 u1 = make_float2(d02.x + d13.y, d02.y - d13.x);  // d02 - i*d13
    float2 u2 = make_float2(s02.x - s13.x, s02.y - s13.y);
    float2 u3 = make_float2(d02.x - d13.y, d02.y + d13.x);  // d02 + i*d13
    float2 E1 = cmul(w1, u1);
    float2 E2 = cmul(w2, u2);
    float2 E3 = cmul(w3, u3);
    y[SWZ(o)] = E0;
    y[SWZ(o + m)] = E1;
    y[SWZ(o + 2 * m)] = E2;
    y[SWZ(o + 3 * m)] = E3;
    __syncthreads();
    float2* tmp = x; x = y; y = tmp;
  }
  // After the loop: x == bufA[ff] (stage-3 output), y == bufB[ff].
  // Final radix-2 is twiddle-free; fuse into the unpack (reconstruct Zk, Z512-k
  // directly from stage-3 output in x), skipping one LDS round-trip + barrier.
  for (int k = v; k < 258; k += 128) {
    float2 Zk, Zm;
    if (k <= 255) {
      float2 a0 = x[SWZ(k)], a1 = x[SWZ(k + 256)];
      Zk = make_float2(a0.x + a1.x, a0.y + a1.y);
    } else {
      float2 a0 = x[SWZ(k - 256)], a1 = x[SWZ(k)];
      Zk = make_float2(a0.x - a1.x, a0.y - a1.y);
    }
    int m2 = (NFFT - k) & (NFFT - 1);
    if (k == 0 || k == 256) {
      Zm = Zk;                       // structural: X1.im = X2.im = 0 exactly
    } else if (m2 >= 256) {          // k in 1..255
      float2 b0 = x[SWZ(m2 - 256)], b1 = x[SWZ(m2)];
      Zm = make_float2(b0.x - b1.x, b0.y - b1.y);
    } else {                         // k == 257 -> m2 = 255
      float2 b0 = x[SWZ(m2)], b1 = x[SWZ(m2 + 256)];
      Zm = make_float2(b0.x + b1.x, b0.y + b1.y);
    }
    y[SWZ(k)] = make_float2(0.5f * (Zk.x + Zm.x), 0.5f * (Zk.y - Zm.y));
    y[SWZ(258 + k)] = make_float2(0.5f * (Zk.y + Zm.y), 0.5f * (Zm.x - Zk.x));
  }
  __syncthreads();

  // epilogue: compute per-bin outputs, hold mspec/squares in registers
  // (static [3] arrays, fully unrolled -> stays in VGPRs)
  unsigned ob0 = (unsigned)fr0 * ROW;
  unsigned ob1 = (unsigned)fr1 * ROW;
  float mspA[3], mspB[3], sql[3], sqs[3], sqc[3];
#pragma unroll
  for (int ki = 0; ki < 3; ++ki) {
    int k = v + 128 * ki;
    if (k <= 256) {
      EB e0 = epilogue_bin(y, 0, out, ob0, k, h0);
      EB e1 = epilogue_bin(y, 258, out, ob1, k, h1);
      mspA[ki] = e0.msp;
      mspB[ki] = e1.msp;
      sql[ki] = (h0 ? e0.lg * e0.lg : 0.f) + (h1 ? e1.lg * e1.lg : 0.f);
      sqs[ki] = (h0 ? e0.sv * e0.sv : 0.f) + (h1 ? e1.sv * e1.sv : 0.f);
      sqc[ki] = (h0 ? e0.cv * e0.cv : 0.f) + (h1 ? e1.cv * e1.cv : 0.f);
    }
  }
  __syncthreads();   // all reads of y (spectra) done -> bufB reusable

  // park: mspec (both frames) in bufB[ff]; squares (sqf) in bufA[ff]
  float* mspSh = (float*)&bufB[ff][0];  // [0..257) frame0, [258..515) frame1
  float* sqf = (float*)&bufA[ff][0];    // ch0 at [0..257), ch2 at [258..515), ch3 at [516..773)
#pragma unroll
  for (int ki = 0; ki < 3; ++ki) {
    int k = v + 128 * ki;
    if (k <= 256) {
      mspSh[k] = mspA[ki];
      mspSh[258 + k] = mspB[ki];
      sqf[k] = sql[ki];
      sqf[258 + k] = sqs[ki];
      sqf[516 + k] = sqc[ki];
    }
  }
  __syncthreads();

  // sparse mel for both frames of this FFT
  for (int m = v; m < NBINS; m += 128) {
    int lo = lohi[m], hi = lohi[NBINS + m];
    float a0 = 0.0f, a1 = 0.0f;
    for (int f = lo; f <= hi; ++f) {
      float w = fb[f * NBINS + m];
      a0 = fmaf(mspSh[f], w, a0);
      a1 = fmaf(mspSh[258 + f], w, a1);
    }
    if (h0) out[ob0 + NBINS + m] = a0;
    if (h1) out[ob1 + NBINS + m] = a1;
  }

  // combine both FFTs' squares -> compact 771-float partial row per block.
  // sqf has GAPS at 257 and 515 (regions are 258-strided): lidx skips them.
  const float* sq0 = (const float*)&bufA[0][0];
  const float* sq1 = (const float*)&bufA[1][0];
  for (int i = t; i < 771; i += 256) {
    int lidx = i + (i >= 257) + (i >= 514);
    partF[(unsigned)blockIdx.x * 771u + i] = sq0[lidx] + sq1[lidx];
  }
}

// ---------- pcen phase A: local chunk scan from zero -> mend ----------
__global__ __launch_bounds__(320) void k_pcen_a(const float* __restrict__ out,
                                                float* __restrict__ mend, int nframes) {
  int m = threadIdx.x;
  if (m >= NBINS) return;
  int c = blockIdx.x;
  int F0 = c * CHUNK;
  int end = min(F0 + CHUNK, nframes);
  const float SS = 0.025f, OMS = 1.0f - SS;
  float mm = 0.0f;
  int tf = F0;
  for (; tf + 16 <= end; tf += 16) {
    float xs[16];
#pragma unroll
    for (int j = 0; j < 16; ++j) xs[j] = out[(unsigned)(tf + j) * ROW + NBINS + m];
#pragma unroll
    for (int j = 0; j < 16; ++j) mm = OMS * mm + SS * xs[j];
  }
  for (; tf < end; ++tf) mm = OMS * mm + SS * out[(unsigned)tf * ROW + NBINS + m];
  mend[c * NBINS + m] = mm;
}

// ---------- pcen phase C: init from prev 12 chunks' mend (LAM64^12=3.6e-9),
// scan+rewrite ch1; ch1 column-square partials free from registers ----------
__global__ __launch_bounds__(320) void k_pcen_c(float* __restrict__ out,
                                                const float* __restrict__ mend,
                                                float* __restrict__ partC,
                                                int nframes) {
  int m = threadIdx.x;
  if (m >= NBINS) return;
  int c = blockIdx.x;
  int F0 = c * CHUNK;
  int end = min(F0 + CHUNK, nframes);
  const float SS = 0.025f, OMS = 1.0f - SS;
  const float SQ2 = sqrtf(2.0f);
  float mm;
  if (c >= 12) {
    float xs[12];
#pragma unroll
    for (int j = 0; j < 12; ++j) xs[j] = mend[(c - 12 + j) * NBINS + m];
    mm = 0.0f;
#pragma unroll
    for (int j = 0; j < 12; ++j) mm = xs[j] + LAM64 * mm;
  } else {
    mm = 0.0f;
    for (int j = 0; j < c; ++j) mm = mend[j * NBINS + m] + LAM64 * mm;
  }
  float acc1 = 0.0f;
  int tf = F0;
  for (; tf + 16 <= end; tf += 16) {
    float xs[16], ys[16];
#pragma unroll
    for (int j = 0; j < 16; ++j) xs[j] = out[(unsigned)(tf + j) * ROW + NBINS + m];
#pragma unroll
    for (int j = 0; j < 16; ++j) {
      mm = OMS * mm + SS * xs[j];
      float invden = __expf(-0.98f * __logf(mm + 1e-6f));  // 1/den, no division
      float val = fmaf(xs[j], invden, 2.0f);
      float rs = __builtin_amdgcn_rsqf(val);
      ys[j] = val * rs - SQ2;   // sqrt(val) - sqrt(2), ~1ulp
      acc1 = fmaf(ys[j], ys[j], acc1);
    }
#pragma unroll
    for (int j = 0; j < 16; ++j) out[(unsigned)(tf + j) * ROW + NBINS + m] = ys[j];
  }
  for (; tf < end; ++tf) {
    unsigned idx = (unsigned)tf * ROW + NBINS + m;
    float xv = out[idx];
    mm = OMS * mm + SS * xv;
    float invden = __expf(-0.98f * __logf(mm + 1e-6f));
    float val = fmaf(xv, invden, 2.0f);
    float rs = __builtin_amdgcn_rsqf(val);
    float yv = val * rs - SQ2;
    acc1 = fmaf(yv, yv, acc1);
    out[idx] = yv;
  }
  partC[c * NBINS + m] = acc1;
}

// ---------- finalize norms: one block per column (deterministic tree) ----------
__global__ __launch_bounds__(256) void k_norm(const float* __restrict__ partF,
                                              const float* __restrict__ partC,
                                              float* __restrict__ invn,
                                              int nfb, int chunks) {
  __shared__ float red[256];
  int c = blockIdx.x, t = threadIdx.x;
  float s = 0.0f;
  if (c >= 257 && c < 514) {
    int m = c - 257;
    for (int r = t; r < chunks; r += 256) s += partC[r * NBINS + m];
  } else {
    int i = (c < 257) ? c : c - 257;
    for (int r = t; r < nfb; r += 256) s += partF[(unsigned)r * 771u + i];
  }
  red[t] = s;
  __syncthreads();
  for (int o = 128; o > 0; o >>= 1) {
    if (t < o) red[t] += red[t + o];
    __syncthreads();
  }
  if (t == 0) invn[c] = 1.0f / fmaxf(sqrtf(red[0]), 1e-12f);
}

// ---------- scale pass ----------
__global__ __launch_bounds__(256) void k_scale(float4* __restrict__ out4,
                                               const float* __restrict__ invn,
                                               long n4) {
  __shared__ float inv[ROW];
  for (int i = threadIdx.x; i < ROW; i += 256) inv[i] = invn[i];
  __syncthreads();
  long stride = (long)gridDim.x * 256;
  for (long i = (long)blockIdx.x * 256 + threadIdx.x; i < n4; i += stride) {
    float4 v = out4[i];
    int col = (int)((i * 4) % ROW);
    v.x *= inv[col];
    v.y *= inv[col + 1];
    v.z *= inv[col + 2];
    v.w *= inv[col + 3];
    out4[i] = v;
  }
}

extern "C" void kernel_launch(void* const* d_in, const int* in_sizes, int n_in,
                              void* d_out, int out_size, void* d_ws, size_t ws_size,
                              hipStream_t stream) {
  const float* audio = (const float*)d_in[0];
  const float* fb = (const float*)d_in[1];
  int T = in_sizes[0];
  int nframes = 1 + T / HOP;  // center=True, pad = NFFT/2 both sides
  float* out = (float*)d_out;
  int chunks = (nframes + CHUNK - 1) / CHUNK;
  int nfb = (nframes + 3) / 4;

  // ws layout (floats): twg[1024] | mend[chunks*257] | invn[1028] |
  //                     lohi[514](int) | partC[chunks*257] | partF[nfb*771]
  float* wsf = (float*)d_ws;
  float2* twg = (float2*)wsf;
  float* mend = wsf + 1024;
  float* invn = mend + (long)chunks * NBINS;
  int* lohi = (int*)(invn + ROW);
  float* partC = (float*)(lohi + 2 * NBINS);
  float* partF = partC + (long)chunks * NBINS;

  k_prep<<<1, 256, 0, stream>>>(fb, lohi, twg);
  k_fft<<<nfb, 256, 0, stream>>>(audio, fb, lohi, twg, out, partF, T, nframes);
  k_pcen_a<<<chunks, 320, 0, stream>>>(out, mend, nframes);
  k_pcen_c<<<chunks, 320, 0, stream>>>(out, mend, partC, nframes);
  k_norm<<<ROW, 256, 0, stream>>>(partF, partC, invn, nfb, chunks);
  long n4 = (long)nframes * ROW / 4;
  k_scale<<<2048, 256, 0, stream>>>((float4*)out, invn, n4);
}